// Round 1
// baseline (1265.634 us; speedup 1.0000x reference)
//
#include <hip/hip_runtime.h>

constexpr int F_IN = 256;
constexpr int H    = 128;
constexpr int C    = 16;
constexpr int KITER = 10;

// ---------------- degrees / norms / edge weights ----------------

__global__ __launch_bounds__(256) void zero_i32(int* p, int n) {
    int i = blockIdx.x * 256 + threadIdx.x;
    if (i < n) p[i] = 0;
}

__global__ __launch_bounds__(256) void deg_kernel(const int* __restrict__ src,
                                                  const int* __restrict__ dst,
                                                  int* deg_out, int* deg_in, int E) {
    int i = blockIdx.x * 256 + threadIdx.x;
    if (i < E) {
        atomicAdd(&deg_out[src[i]], 1);
        atomicAdd(&deg_in[dst[i]], 1);
    }
}

__global__ __launch_bounds__(256) void norm_kernel(const int* __restrict__ deg_out,
                                                   const int* __restrict__ deg_in,
                                                   float* __restrict__ norm_src,
                                                   float* __restrict__ norm_dst, int N) {
    int i = blockIdx.x * 256 + threadIdx.x;
    if (i < N) {
        int a = deg_out[i];
        int b = deg_in[i];
        norm_src[i] = (a > 0) ? rsqrtf((float)a) : 0.0f;
        norm_dst[i] = (b > 0) ? rsqrtf((float)b) : 0.0f;
    }
}

__global__ __launch_bounds__(256) void ew_kernel(const int* __restrict__ src,
                                                 const int* __restrict__ dst,
                                                 const float* __restrict__ ns,
                                                 const float* __restrict__ nd,
                                                 float* __restrict__ ew, int E) {
    int i = blockIdx.x * 256 + threadIdx.x;
    if (i < E) ew[i] = 0.9f * ns[src[i]] * nd[dst[i]];
}

// ---------------- fused 3-layer MLP ----------------
// Block = 256 threads, 32 nodes/block. feat rows staged in LDS;
// h1, h2 kept in LDS; only the final [N,16] written to global.
// Thread map (layers 0/1): j = t&127 (output col), i0 = (t>>7)*16 (node group).

__global__ __launch_bounds__(256) void mlp_fused(
    const float* __restrict__ feat,
    const float* __restrict__ W0, const float* __restrict__ b0,
    const float* __restrict__ W1, const float* __restrict__ b1,
    const float* __restrict__ W2, const float* __restrict__ b2,
    float* __restrict__ hout, int M)
{
    // 32*256 floats (feat, later reused as h2) + 32*128 floats (h1) = 48 KB
    __shared__ float smem[32 * 256 + 32 * 128];
    float* sF = smem;             // [32][256], later aliased as sH2 [32][128]
    float* sH = smem + 32 * 256;  // [32][128]

    const int t    = threadIdx.x;
    const int base = blockIdx.x * 32;

    // stage 32 feature rows (8192 floats = 2048 float4)
    {
        const float4* g4 = reinterpret_cast<const float4*>(feat + (size_t)base * F_IN);
        float4*       s4 = reinterpret_cast<float4*>(sF);
#pragma unroll
        for (int r = 0; r < 8; ++r) s4[r * 256 + t] = g4[r * 256 + t];
    }
    __syncthreads();

    const int j  = t & 127;
    const int i0 = (t >> 7) * 16;

    float acc[16];

    // ---- layer 0: [32,256] @ [256,128] ----
#pragma unroll
    for (int ii = 0; ii < 16; ++ii) acc[ii] = 0.0f;
    {
        const float4* s4 = reinterpret_cast<const float4*>(sF);
        for (int k4 = 0; k4 < F_IN / 4; ++k4) {
            const int k = k4 * 4;
            float w0 = W0[(k + 0) * H + j];
            float w1 = W0[(k + 1) * H + j];
            float w2 = W0[(k + 2) * H + j];
            float w3 = W0[(k + 3) * H + j];
#pragma unroll
            for (int ii = 0; ii < 16; ++ii) {
                float4 a = s4[(i0 + ii) * (F_IN / 4) + k4];
                acc[ii] = fmaf(a.w, w3, fmaf(a.z, w2, fmaf(a.y, w1, fmaf(a.x, w0, acc[ii]))));
            }
        }
    }
    {
        float bj = b0[j];
#pragma unroll
        for (int ii = 0; ii < 16; ++ii) sH[(i0 + ii) * H + j] = fmaxf(acc[ii] + bj, 0.0f);
    }
    __syncthreads();

    // ---- layer 1: [32,128] @ [128,128] ----
#pragma unroll
    for (int ii = 0; ii < 16; ++ii) acc[ii] = 0.0f;
    {
        const float4* s4 = reinterpret_cast<const float4*>(sH);
        for (int k4 = 0; k4 < H / 4; ++k4) {
            const int k = k4 * 4;
            float w0 = W1[(k + 0) * H + j];
            float w1 = W1[(k + 1) * H + j];
            float w2 = W1[(k + 2) * H + j];
            float w3 = W1[(k + 3) * H + j];
#pragma unroll
            for (int ii = 0; ii < 16; ++ii) {
                float4 a = s4[(i0 + ii) * (H / 4) + k4];
                acc[ii] = fmaf(a.w, w3, fmaf(a.z, w2, fmaf(a.y, w1, fmaf(a.x, w0, acc[ii]))));
            }
        }
    }
    float* sH2 = sF;  // reuse feat region (layer-0 reads of sF finished before last sync)
    {
        float bj = b1[j];
#pragma unroll
        for (int ii = 0; ii < 16; ++ii) sH2[(i0 + ii) * H + j] = fmaxf(acc[ii] + bj, 0.0f);
    }
    __syncthreads();

    // ---- layer 2: [32,128] @ [128,16] ----
    {
        const int c = t & 15;
        const int q = t >> 4;  // 0..15 -> handles nodes q and q+16
        float a0 = 0.0f, a1 = 0.0f;
        for (int k = 0; k < H; ++k) {
            float w = W2[k * C + c];
            a0 = fmaf(sH2[q * H + k], w, a0);
            a1 = fmaf(sH2[(q + 16) * H + k], w, a1);
        }
        float bc = b2[c];
        hout[(size_t)(base + q) * C + c]      = a0 + bc;
        hout[(size_t)(base + q + 16) * C + c] = a1 + bc;
    }
}

// ---------------- propagation ----------------

__global__ __launch_bounds__(256) void prop_init(const float* __restrict__ h0,
                                                 float* __restrict__ hn, int n) {
    int i = blockIdx.x * 256 + threadIdx.x;
    if (i < n) hn[i] = 0.1f * h0[i];
}

// 16 threads per edge (one per channel). w already includes 0.9*norm_src*norm_dst.
__global__ __launch_bounds__(256) void prop_edge(const int* __restrict__ src,
                                                 const int* __restrict__ dst,
                                                 const float* __restrict__ ew,
                                                 const float* __restrict__ hc,
                                                 float* __restrict__ hn, int E) {
    int gid = blockIdx.x * 256 + threadIdx.x;
    int e = gid >> 4;
    if (e < E) {
        int   c = gid & 15;
        int   s = src[e];
        int   d = dst[e];
        float w = ew[e];
        atomicAdd(&hn[(size_t)d * C + c], w * hc[(size_t)s * C + c]);
    }
}

// ---------------- launch ----------------

extern "C" void kernel_launch(void* const* d_in, const int* in_sizes, int n_in,
                              void* d_out, int out_size, void* d_ws, size_t ws_size,
                              hipStream_t stream) {
    const float* feat = (const float*)d_in[0];
    const float* W0   = (const float*)d_in[1];
    const float* b0   = (const float*)d_in[2];
    const float* W1   = (const float*)d_in[3];
    const float* b1   = (const float*)d_in[4];
    const float* W2   = (const float*)d_in[5];
    const float* b2   = (const float*)d_in[6];
    const int*   src  = (const int*)d_in[7];
    const int*   dst  = (const int*)d_in[8];

    const int N = in_sizes[0] / F_IN;   // 100000
    const int E = in_sizes[7];          // 1600000

    char* ws = (char*)d_ws;
    float* h0   = (float*)ws; ws += (size_t)N * C * 4;
    float* ha   = (float*)ws; ws += (size_t)N * C * 4;
    float* hb   = (float*)ws; ws += (size_t)N * C * 4;
    float* ew   = (float*)ws; ws += (size_t)E * 4;
    int*   dego = (int*)ws;   ws += (size_t)N * 4;
    int*   degi = (int*)ws;   ws += (size_t)N * 4;   // contiguous after dego
    float* ns   = (float*)ws; ws += (size_t)N * 4;
    float* nd   = (float*)ws; ws += (size_t)N * 4;

    zero_i32<<<(2 * N + 255) / 256, 256, 0, stream>>>(dego, 2 * N);
    deg_kernel<<<(E + 255) / 256, 256, 0, stream>>>(src, dst, dego, degi, E);
    norm_kernel<<<(N + 255) / 256, 256, 0, stream>>>(dego, degi, ns, nd, N);
    ew_kernel<<<(E + 255) / 256, 256, 0, stream>>>(src, dst, ns, nd, ew, E);

    mlp_fused<<<N / 32, 256, 0, stream>>>(feat, W0, b0, W1, b1, W2, b2, h0, N);

    const float* cur = h0;
    for (int it = 0; it < KITER; ++it) {
        float* nxt = (it == KITER - 1) ? (float*)d_out : ((it & 1) ? hb : ha);
        prop_init<<<(N * C + 255) / 256, 256, 0, stream>>>(h0, nxt, N * C);
        prop_edge<<<((E * 16) + 255) / 256, 256, 0, stream>>>(src, dst, ew, cur, nxt, E);
        cur = nxt;
    }
}

// Round 2
// 807.134 us; speedup vs baseline: 1.5681x; 1.5681x over previous
//
#include <hip/hip_runtime.h>

typedef _Float16 half8 __attribute__((ext_vector_type(8)));
typedef _Float16 half4 __attribute__((ext_vector_type(4)));
typedef float f32x4 __attribute__((ext_vector_type(4)));

constexpr int F_IN = 256;
constexpr int H    = 128;
constexpr int C    = 16;
constexpr int KITER = 10;

// ---------------- degrees / norms ----------------

__global__ __launch_bounds__(256) void zero_i32(int* p, int n) {
    int i = blockIdx.x * 256 + threadIdx.x;
    if (i < n) p[i] = 0;
}

__global__ __launch_bounds__(256) void deg_kernel(const int* __restrict__ src,
                                                  const int* __restrict__ dst,
                                                  int* deg_out, int* deg_in, int E) {
    int i = blockIdx.x * 256 + threadIdx.x;
    if (i < E) {
        atomicAdd(&deg_out[src[i]], 1);
        atomicAdd(&deg_in[dst[i]], 1);
    }
}

__global__ __launch_bounds__(256) void norm_kernel(const int* __restrict__ deg_out,
                                                   const int* __restrict__ deg_in,
                                                   float* __restrict__ norm_src,
                                                   float* __restrict__ norm_dst, int N) {
    int i = blockIdx.x * 256 + threadIdx.x;
    if (i < N) {
        int a = deg_out[i];
        int b = deg_in[i];
        norm_src[i] = (a > 0) ? rsqrtf((float)a) : 0.0f;
        norm_dst[i] = (b > 0) ? rsqrtf((float)b) : 0.0f;
    }
}

// ---------------- CSR build: scan + scatter ----------------

__global__ __launch_bounds__(256) void scan1(const int* __restrict__ d, int* __restrict__ off,
                                             int* __restrict__ bsum, int N) {
    __shared__ int s[256];
    int t = threadIdx.x, i = blockIdx.x * 256 + t;
    int v = (i < N) ? d[i] : 0;
    s[t] = v;
    __syncthreads();
    for (int dd = 1; dd < 256; dd <<= 1) {
        int x = (t >= dd) ? s[t - dd] : 0;
        __syncthreads();
        s[t] += x;
        __syncthreads();
    }
    if (i < N) off[i] = s[t] - v;          // exclusive within block
    if (t == 255) bsum[blockIdx.x] = s[255];
}

__global__ __launch_bounds__(512) void scan2(int* __restrict__ bsum, int nb) {
    __shared__ int s[512];
    int t = threadIdx.x;
    int v = (t < nb) ? bsum[t] : 0;
    s[t] = v;
    __syncthreads();
    for (int dd = 1; dd < 512; dd <<= 1) {
        int x = (t >= dd) ? s[t - dd] : 0;
        __syncthreads();
        s[t] += x;
        __syncthreads();
    }
    if (t < nb) bsum[t] = s[t] - v;        // exclusive block bases
}

__global__ __launch_bounds__(256) void scan3(int* __restrict__ off, const int* __restrict__ bsum,
                                             int* __restrict__ cursor, int N) {
    int i = blockIdx.x * 256 + threadIdx.x;
    if (i < N) {
        int o = off[i] + bsum[blockIdx.x];
        off[i] = o;
        cursor[i] = o;
    }
}

__global__ __launch_bounds__(256) void scatter_k(const int* __restrict__ src, const int* __restrict__ dst,
                                                 const float* __restrict__ ns, const float* __restrict__ nd,
                                                 int* cursor, unsigned long long* __restrict__ epack, int E) {
    int e = blockIdx.x * 256 + threadIdx.x;
    if (e < E) {
        int s = src[e], d = dst[e];
        float w = 0.9f * ns[s] * nd[d];
        int p = atomicAdd(&cursor[d], 1);
        epack[p] = (unsigned long long)(unsigned int)s |
                   ((unsigned long long)__float_as_uint(w) << 32);
    }
}

// ---------------- weight packing to MFMA fragment order ----------------
// out[(nt*KS + ks)*64 + l][j] = (f16) W[ ks*32 + (l>>4)*8 + j ][ nt*16 + (l&15) ]

__global__ __launch_bounds__(256) void wpack(const float* __restrict__ W, half8* __restrict__ out,
                                             int K, int Ncols) {
    int tid = blockIdx.x * 256 + threadIdx.x;
    int KS = K / 32;
    int NT = Ncols / 16;
    int total = NT * KS * 64;
    if (tid < total) {
        int l  = tid & 63;
        int ks = (tid >> 6) % KS;
        int nt = tid / (KS * 64);
        int col = nt * 16 + (l & 15);
        int kb  = ks * 32 + ((l >> 4) * 8);
        half8 h;
#pragma unroll
        for (int j = 0; j < 8; ++j) h[j] = (_Float16)W[(kb + j) * Ncols + col];
        out[tid] = h;
    }
}

// ---------------- fused MLP via f16 MFMA ----------------
// 64 nodes/block, 4 waves; wave w owns rows w*16..w*16+15 end to end.
// sA: f16[64][256] (32KB, XOR-swizzled), sH1: f16[64][128] (16KB).
// sA region reused for H2 after a barrier.

__global__ __launch_bounds__(256) void mlp_mfma(
    const float* __restrict__ feat,
    const half8* __restrict__ B0, const float* __restrict__ b0,
    const half8* __restrict__ B1, const float* __restrict__ b1,
    const half8* __restrict__ B2, const float* __restrict__ b2,
    float* __restrict__ hout, int N)
{
    __shared__ __align__(16) char lds[64 * 512 + 64 * 256];
    char* sA  = lds;             // f16[64][256] rows of 512B; later f16[64][128] H2
    char* sH1 = lds + 64 * 512;  // f16[64][128] rows of 256B

    const int t    = threadIdx.x;
    const int base = blockIdx.x * 64;
    const int l    = t & 63;
    const int w    = t >> 6;

    // ---- stage 64 feature rows as f16, swizzled ----
    {
        const float4* g4 = reinterpret_cast<const float4*>(feat);
        const int maxq = N * 64 - 1;  // total float4 count - 1
#pragma unroll
        for (int i = 0; i < 16; ++i) {
            int q = base * 64 + i * 256 + t;
            if (q > maxq) q = maxq;
            float4 a = g4[q];
            int lq   = i * 256 + t;
            int row  = lq >> 6;
            int colb = (lq & 63) * 8;   // byte offset within 512B row
            int byte = row * 512 + (colb ^ ((row & 7) << 4));
            half4 h = {(_Float16)a.x, (_Float16)a.y, (_Float16)a.z, (_Float16)a.w};
            *reinterpret_cast<half4*>(sA + byte) = h;
        }
    }
    __syncthreads();

    const int arow = w * 16 + (l & 15);
    const f32x4 zero = {0.0f, 0.0f, 0.0f, 0.0f};

    // ---- layer 0: [16 rows x 256] @ [256 x 128] per wave ----
    f32x4 acc0[8];
#pragma unroll
    for (int nt = 0; nt < 8; ++nt) acc0[nt] = zero;
    for (int ks = 0; ks < 8; ++ks) {
        int byte = arow * 512 + (((ks * 64) + ((l >> 4) * 16)) ^ ((arow & 7) << 4));
        half8 a = *reinterpret_cast<const half8*>(sA + byte);
#pragma unroll
        for (int nt = 0; nt < 8; ++nt) {
            half8 b = B0[(nt * 8 + ks) * 64 + l];
            acc0[nt] = __builtin_amdgcn_mfma_f32_16x16x32_f16(a, b, acc0[nt], 0, 0, 0);
        }
    }
    // bias + relu -> sH1 (f16)
#pragma unroll
    for (int nt = 0; nt < 8; ++nt) {
        float bb = b0[nt * 16 + (l & 15)];
#pragma unroll
        for (int r = 0; r < 4; ++r) {
            int row  = w * 16 + (l >> 4) * 4 + r;
            int colb = (nt * 16 + (l & 15)) * 2;
            int byte = row * 256 + (colb ^ ((row & 7) << 4));
            *reinterpret_cast<_Float16*>(sH1 + byte) = (_Float16)fmaxf(acc0[nt][r] + bb, 0.0f);
        }
    }

    // ---- layer 1: [16 x 128] @ [128 x 128] ----
    f32x4 acc1[8];
#pragma unroll
    for (int nt = 0; nt < 8; ++nt) acc1[nt] = zero;
    for (int ks = 0; ks < 4; ++ks) {
        int byte = arow * 256 + (((ks * 64) + ((l >> 4) * 16)) ^ ((arow & 7) << 4));
        half8 a = *reinterpret_cast<const half8*>(sH1 + byte);
#pragma unroll
        for (int nt = 0; nt < 8; ++nt) {
            half8 b = B1[(nt * 4 + ks) * 64 + l];
            acc1[nt] = __builtin_amdgcn_mfma_f32_16x16x32_f16(a, b, acc1[nt], 0, 0, 0);
        }
    }

    __syncthreads();  // everyone is done reading sA -> safe to reuse as H2

    // bias + relu -> H2 (in sA region, f16[64][128])
#pragma unroll
    for (int nt = 0; nt < 8; ++nt) {
        float bb = b1[nt * 16 + (l & 15)];
#pragma unroll
        for (int r = 0; r < 4; ++r) {
            int row  = w * 16 + (l >> 4) * 4 + r;
            int colb = (nt * 16 + (l & 15)) * 2;
            int byte = row * 256 + (colb ^ ((row & 7) << 4));
            *reinterpret_cast<_Float16*>(sA + byte) = (_Float16)fmaxf(acc1[nt][r] + bb, 0.0f);
        }
    }

    // ---- layer 2: [16 x 128] @ [128 x 16] ----
    f32x4 acc2 = zero;
    for (int ks = 0; ks < 4; ++ks) {
        int byte = arow * 256 + (((ks * 64) + ((l >> 4) * 16)) ^ ((arow & 7) << 4));
        half8 a = *reinterpret_cast<const half8*>(sA + byte);
        half8 b = B2[ks * 64 + l];
        acc2 = __builtin_amdgcn_mfma_f32_16x16x32_f16(a, b, acc2, 0, 0, 0);
    }
    {
        float bb = b2[l & 15];
#pragma unroll
        for (int r = 0; r < 4; ++r) {
            int row  = w * 16 + (l >> 4) * 4 + r;
            int node = base + row;
            if (node < N) hout[(size_t)node * C + (l & 15)] = acc2[r] + bb;
        }
    }
}

// ---------------- propagation: CSR gather, no atomics ----------------
// 16 lanes per node (one per channel); edge stream uniform within the group.

__global__ __launch_bounds__(256) void gather_k(const unsigned long long* __restrict__ ep,
                                                const int* __restrict__ off,
                                                const float* __restrict__ hc,
                                                const float* __restrict__ h0,
                                                float* __restrict__ hn, int N, int E) {
    int gid = blockIdx.x * 256 + threadIdx.x;
    int node = gid >> 4;
    if (node >= N) return;
    int c = gid & 15;
    int o0 = off[node];
    int o1 = (node + 1 < N) ? off[node + 1] : E;
    float acc = 0.1f * h0[gid];
    for (int o = o0; o < o1; ++o) {
        unsigned long long v = ep[o];
        int s   = (int)(unsigned int)(v & 0xffffffffULL);
        float wt = __uint_as_float((unsigned int)(v >> 32));
        acc = fmaf(wt, hc[s * 16 + c], acc);
    }
    hn[gid] = acc;
}

// ---------------- launch ----------------

extern "C" void kernel_launch(void* const* d_in, const int* in_sizes, int n_in,
                              void* d_out, int out_size, void* d_ws, size_t ws_size,
                              hipStream_t stream) {
    const float* feat = (const float*)d_in[0];
    const float* W0   = (const float*)d_in[1];
    const float* b0   = (const float*)d_in[2];
    const float* W1   = (const float*)d_in[3];
    const float* b1   = (const float*)d_in[4];
    const float* W2   = (const float*)d_in[5];
    const float* b2   = (const float*)d_in[6];
    const int*   src  = (const int*)d_in[7];
    const int*   dst  = (const int*)d_in[8];

    const int N = in_sizes[0] / F_IN;   // 100000
    const int E = in_sizes[7];          // 1600000
    const int NB = (N + 255) / 256;     // 391

    char* ws = (char*)d_ws;
    float* h0   = (float*)ws; ws += (size_t)N * C * 4;
    float* ha   = (float*)ws; ws += (size_t)N * C * 4;
    float* hb   = (float*)ws; ws += (size_t)N * C * 4;
    int*   dego = (int*)ws;   ws += (size_t)N * 4;
    int*   degi = (int*)ws;   ws += (size_t)N * 4;   // contiguous after dego
    float* ns   = (float*)ws; ws += (size_t)N * 4;
    float* nd   = (float*)ws; ws += (size_t)N * 4;
    int*   off  = (int*)ws;   ws += (size_t)N * 4;
    int*   cur_ = (int*)ws;   ws += (size_t)N * 4;
    int*   bsum = (int*)ws;   ws += 512 * 4;
    // keep 16B alignment for half8 / 8B for epack (all prior sizes are x16)
    unsigned long long* epack = (unsigned long long*)ws; ws += (size_t)E * 8;
    half8* B0 = (half8*)ws; ws += 4096 * 16;
    half8* B1 = (half8*)ws; ws += 2048 * 16;
    half8* B2 = (half8*)ws; ws += 256 * 16;

    zero_i32<<<(2 * N + 255) / 256, 256, 0, stream>>>(dego, 2 * N);
    deg_kernel<<<(E + 255) / 256, 256, 0, stream>>>(src, dst, dego, degi, E);
    norm_kernel<<<NB, 256, 0, stream>>>(dego, degi, ns, nd, N);

    scan1<<<NB, 256, 0, stream>>>(degi, off, bsum, N);
    scan2<<<1, 512, 0, stream>>>(bsum, NB);
    scan3<<<NB, 256, 0, stream>>>(off, bsum, cur_, N);
    scatter_k<<<(E + 255) / 256, 256, 0, stream>>>(src, dst, ns, nd, cur_, epack, E);

    wpack<<<16, 256, 0, stream>>>(W0, B0, 256, 128);
    wpack<<<8, 256, 0, stream>>>(W1, B1, 128, 128);
    wpack<<<1, 256, 0, stream>>>(W2, B2, 128, 16);

    mlp_mfma<<<(N + 63) / 64, 256, 0, stream>>>(feat, B0, b0, B1, b1, B2, b2, h0, N);

    const float* cur = h0;
    for (int it = 0; it < KITER; ++it) {
        float* nxt = (it == KITER - 1) ? (float*)d_out : ((it & 1) ? hb : ha);
        gather_k<<<(N * C + 255) / 256, 256, 0, stream>>>(epack, off, cur, h0, nxt, N, E);
        cur = nxt;
    }
}

// Round 3
// 705.207 us; speedup vs baseline: 1.7947x; 1.1445x over previous
//
#include <hip/hip_runtime.h>

typedef _Float16 half8 __attribute__((ext_vector_type(8)));
typedef _Float16 half4 __attribute__((ext_vector_type(4)));
typedef float f32x4 __attribute__((ext_vector_type(4)));

constexpr int F_IN = 256;
constexpr int H    = 128;
constexpr int C    = 16;
constexpr int KITER = 10;

constexpr int RANGE = 16384;  // nodes per LDS histogram range (64 KB)
constexpr int PCH   = 32;     // edge chunks

// ---------------- LDS-privatized histogram (no global atomics) ----------------
// grid = PCH * R blocks; block (p, r) counts idx values in [r*RANGE, r*RANGE+RANGE)
// over edge chunk p, flushes non-atomic to partial[p*N + i].

__global__ __launch_bounds__(256) void hist_k(const int* __restrict__ idx,
                                              int* __restrict__ partial,
                                              int N, int E, int R, int chunk) {
    __shared__ int cnt[RANGE];
    const int p  = blockIdx.x / R;
    const int r  = blockIdx.x % R;
    const int lo = r * RANGE;
    const int hi = min(lo + RANGE, N);
    const int t  = threadIdx.x;
    for (int i = t; i < RANGE; i += 256) cnt[i] = 0;
    __syncthreads();
    const int e0 = p * chunk, e1 = min(e0 + chunk, E);
    for (int e = e0 + t; e < e1; e += 256) {
        int d = idx[e];
        if (d >= lo && d < hi) atomicAdd(&cnt[d - lo], 1);
    }
    __syncthreads();
    for (int i = lo + t; i < hi; i += 256) partial[(size_t)p * N + i] = cnt[i - lo];
}

// deg[i] = sum_p partial[p][i]
__global__ __launch_bounds__(256) void colsum_k(const int* __restrict__ partial,
                                                int* __restrict__ deg, int N) {
    int i = blockIdx.x * 256 + threadIdx.x;
    if (i < N) {
        int s = 0;
        for (int p = 0; p < PCH; ++p) s += partial[(size_t)p * N + i];
        deg[i] = s;
    }
}

// in-place exclusive prefix along p; deg[i] = total
__global__ __launch_bounds__(256) void colprefix_k(int* __restrict__ partial,
                                                   int* __restrict__ deg, int N) {
    int i = blockIdx.x * 256 + threadIdx.x;
    if (i < N) {
        int run = 0;
        for (int p = 0; p < PCH; ++p) {
            size_t q = (size_t)p * N + i;
            int v = partial[q];
            partial[q] = run;
            run += v;
        }
        deg[i] = run;
    }
}

__global__ __launch_bounds__(256) void norm_kernel(const int* __restrict__ deg_out,
                                                   const int* __restrict__ deg_in,
                                                   float* __restrict__ norm_src,
                                                   float* __restrict__ norm_dst, int N) {
    int i = blockIdx.x * 256 + threadIdx.x;
    if (i < N) {
        int a = deg_out[i];
        int b = deg_in[i];
        norm_src[i] = (a > 0) ? rsqrtf((float)a) : 0.0f;
        norm_dst[i] = (b > 0) ? rsqrtf((float)b) : 0.0f;
    }
}

// ---------------- scan for CSR offsets ----------------

__global__ __launch_bounds__(256) void scan1(const int* __restrict__ d, int* __restrict__ off,
                                             int* __restrict__ bsum, int N) {
    __shared__ int s[256];
    int t = threadIdx.x, i = blockIdx.x * 256 + t;
    int v = (i < N) ? d[i] : 0;
    s[t] = v;
    __syncthreads();
    for (int dd = 1; dd < 256; dd <<= 1) {
        int x = (t >= dd) ? s[t - dd] : 0;
        __syncthreads();
        s[t] += x;
        __syncthreads();
    }
    if (i < N) off[i] = s[t] - v;
    if (t == 255) bsum[blockIdx.x] = s[255];
}

__global__ __launch_bounds__(512) void scan2(int* __restrict__ bsum, int nb) {
    __shared__ int s[512];
    int t = threadIdx.x;
    int v = (t < nb) ? bsum[t] : 0;
    s[t] = v;
    __syncthreads();
    for (int dd = 1; dd < 512; dd <<= 1) {
        int x = (t >= dd) ? s[t - dd] : 0;
        __syncthreads();
        s[t] += x;
        __syncthreads();
    }
    if (t < nb) bsum[t] = s[t] - v;
}

__global__ __launch_bounds__(256) void scan3(int* __restrict__ off, const int* __restrict__ bsum,
                                             int N) {
    int i = blockIdx.x * 256 + threadIdx.x;
    if (i < N) off[i] += bsum[blockIdx.x];
}

// ---------------- CSR scatter (LDS ranks, no global atomics) ----------------

__global__ __launch_bounds__(256) void scatter2_k(const int* __restrict__ src,
                                                  const int* __restrict__ dst,
                                                  const float* __restrict__ ns,
                                                  const float* __restrict__ nd,
                                                  const int* __restrict__ off,
                                                  const int* __restrict__ pprefix,
                                                  unsigned long long* __restrict__ epack,
                                                  int N, int E, int R, int chunk) {
    __shared__ int cnt[RANGE];
    const int p  = blockIdx.x / R;
    const int r  = blockIdx.x % R;
    const int lo = r * RANGE;
    const int hi = min(lo + RANGE, N);
    const int t  = threadIdx.x;
    for (int i = t; i < RANGE; i += 256) cnt[i] = 0;
    __syncthreads();
    const int e0 = p * chunk, e1 = min(e0 + chunk, E);
    for (int e = e0 + t; e < e1; e += 256) {
        int d = dst[e];
        if (d >= lo && d < hi) {
            int rank = atomicAdd(&cnt[d - lo], 1);
            int s = src[e];
            float w = 0.9f * ns[s] * nd[d];
            int pos = off[d] + pprefix[(size_t)p * N + d] + rank;
            epack[pos] = (unsigned long long)(unsigned int)s |
                         ((unsigned long long)__float_as_uint(w) << 32);
        }
    }
}

// ---------------- weight packing to MFMA fragment order ----------------

__global__ __launch_bounds__(256) void wpack(const float* __restrict__ W, half8* __restrict__ out,
                                             int K, int Ncols) {
    int tid = blockIdx.x * 256 + threadIdx.x;
    int KS = K / 32;
    int NT = Ncols / 16;
    int total = NT * KS * 64;
    if (tid < total) {
        int l  = tid & 63;
        int ks = (tid >> 6) % KS;
        int nt = tid / (KS * 64);
        int col = nt * 16 + (l & 15);
        int kb  = ks * 32 + ((l >> 4) * 8);
        half8 h;
#pragma unroll
        for (int j = 0; j < 8; ++j) h[j] = (_Float16)W[(kb + j) * Ncols + col];
        out[tid] = h;
    }
}

// ---------------- fused MLP via f16 MFMA ----------------

__global__ __launch_bounds__(256) void mlp_mfma(
    const float* __restrict__ feat,
    const half8* __restrict__ B0, const float* __restrict__ b0,
    const half8* __restrict__ B1, const float* __restrict__ b1,
    const half8* __restrict__ B2, const float* __restrict__ b2,
    float* __restrict__ hout, int N)
{
    __shared__ __align__(16) char lds[64 * 512 + 64 * 256];
    char* sA  = lds;             // f16[64][256] rows of 512B; later f16[64][128] H2
    char* sH1 = lds + 64 * 512;  // f16[64][128] rows of 256B

    const int t    = threadIdx.x;
    const int base = blockIdx.x * 64;
    const int l    = t & 63;
    const int w    = t >> 6;

    // ---- stage 64 feature rows as f16, swizzled ----
    {
        const float4* g4 = reinterpret_cast<const float4*>(feat);
        const int maxq = N * 64 - 1;
#pragma unroll
        for (int i = 0; i < 16; ++i) {
            int q = base * 64 + i * 256 + t;
            if (q > maxq) q = maxq;
            float4 a = g4[q];
            int lq   = i * 256 + t;
            int row  = lq >> 6;
            int colb = (lq & 63) * 8;
            int byte = row * 512 + (colb ^ ((row & 7) << 4));
            half4 h = {(_Float16)a.x, (_Float16)a.y, (_Float16)a.z, (_Float16)a.w};
            *reinterpret_cast<half4*>(sA + byte) = h;
        }
    }
    __syncthreads();

    const int arow = w * 16 + (l & 15);
    const f32x4 zero = {0.0f, 0.0f, 0.0f, 0.0f};

    // ---- layer 0: [16 rows x 256] @ [256 x 128] per wave ----
    f32x4 acc0[8];
#pragma unroll
    for (int nt = 0; nt < 8; ++nt) acc0[nt] = zero;
    for (int ks = 0; ks < 8; ++ks) {
        int byte = arow * 512 + (((ks * 64) + ((l >> 4) * 16)) ^ ((arow & 7) << 4));
        half8 a = *reinterpret_cast<const half8*>(sA + byte);
#pragma unroll
        for (int nt = 0; nt < 8; ++nt) {
            half8 b = B0[(nt * 8 + ks) * 64 + l];
            acc0[nt] = __builtin_amdgcn_mfma_f32_16x16x32_f16(a, b, acc0[nt], 0, 0, 0);
        }
    }
#pragma unroll
    for (int nt = 0; nt < 8; ++nt) {
        float bb = b0[nt * 16 + (l & 15)];
#pragma unroll
        for (int r = 0; r < 4; ++r) {
            int row  = w * 16 + (l >> 4) * 4 + r;
            int colb = (nt * 16 + (l & 15)) * 2;
            int byte = row * 256 + (colb ^ ((row & 7) << 4));
            *reinterpret_cast<_Float16*>(sH1 + byte) = (_Float16)fmaxf(acc0[nt][r] + bb, 0.0f);
        }
    }

    // ---- layer 1: [16 x 128] @ [128 x 128] ----
    f32x4 acc1[8];
#pragma unroll
    for (int nt = 0; nt < 8; ++nt) acc1[nt] = zero;
    for (int ks = 0; ks < 4; ++ks) {
        int byte = arow * 256 + (((ks * 64) + ((l >> 4) * 16)) ^ ((arow & 7) << 4));
        half8 a = *reinterpret_cast<const half8*>(sH1 + byte);
#pragma unroll
        for (int nt = 0; nt < 8; ++nt) {
            half8 b = B1[(nt * 4 + ks) * 64 + l];
            acc1[nt] = __builtin_amdgcn_mfma_f32_16x16x32_f16(a, b, acc1[nt], 0, 0, 0);
        }
    }

    __syncthreads();  // done reading sA -> reuse as H2

#pragma unroll
    for (int nt = 0; nt < 8; ++nt) {
        float bb = b1[nt * 16 + (l & 15)];
#pragma unroll
        for (int r = 0; r < 4; ++r) {
            int row  = w * 16 + (l >> 4) * 4 + r;
            int colb = (nt * 16 + (l & 15)) * 2;
            int byte = row * 256 + (colb ^ ((row & 7) << 4));
            *reinterpret_cast<_Float16*>(sA + byte) = (_Float16)fmaxf(acc1[nt][r] + bb, 0.0f);
        }
    }

    // ---- layer 2: [16 x 128] @ [128 x 16] ----
    f32x4 acc2 = zero;
    for (int ks = 0; ks < 4; ++ks) {
        int byte = arow * 256 + (((ks * 64) + ((l >> 4) * 16)) ^ ((arow & 7) << 4));
        half8 a = *reinterpret_cast<const half8*>(sA + byte);
        half8 b = B2[ks * 64 + l];
        acc2 = __builtin_amdgcn_mfma_f32_16x16x32_f16(a, b, acc2, 0, 0, 0);
    }
    {
        float bb = b2[l & 15];
#pragma unroll
        for (int r = 0; r < 4; ++r) {
            int row  = w * 16 + (l >> 4) * 4 + r;
            int node = base + row;
            if (node < N) hout[(size_t)node * C + (l & 15)] = acc2[r] + bb;
        }
    }
}

// ---------------- propagation: CSR gather, float4 channels ----------------
// 4 threads per node; each owns 4 channels (one 16B load + 4 fmaf per edge).

__global__ __launch_bounds__(256) void gather4(const unsigned long long* __restrict__ ep,
                                               const int* __restrict__ off,
                                               const float4* __restrict__ hc,
                                               const float4* __restrict__ h0,
                                               float4* __restrict__ hn, int N, int E) {
    int gid = blockIdx.x * 256 + threadIdx.x;
    int node = gid >> 2;
    if (node >= N) return;
    int c = gid & 3;
    int o0 = off[node];
    int o1 = (node + 1 < N) ? off[node + 1] : E;
    float4 hv = h0[gid];
    float4 acc = {0.1f * hv.x, 0.1f * hv.y, 0.1f * hv.z, 0.1f * hv.w};
    for (int o = o0; o < o1; ++o) {
        unsigned long long v = ep[o];
        int   s = (int)(unsigned int)v;
        float w = __uint_as_float((unsigned int)(v >> 32));
        float4 x = hc[s * 4 + c];
        acc.x = fmaf(w, x.x, acc.x);
        acc.y = fmaf(w, x.y, acc.y);
        acc.z = fmaf(w, x.z, acc.z);
        acc.w = fmaf(w, x.w, acc.w);
    }
    hn[gid] = acc;
}

// ---------------- launch ----------------

extern "C" void kernel_launch(void* const* d_in, const int* in_sizes, int n_in,
                              void* d_out, int out_size, void* d_ws, size_t ws_size,
                              hipStream_t stream) {
    const float* feat = (const float*)d_in[0];
    const float* W0   = (const float*)d_in[1];
    const float* b0   = (const float*)d_in[2];
    const float* W1   = (const float*)d_in[3];
    const float* b1   = (const float*)d_in[4];
    const float* W2   = (const float*)d_in[5];
    const float* b2   = (const float*)d_in[6];
    const int*   src  = (const int*)d_in[7];
    const int*   dst  = (const int*)d_in[8];

    const int N = in_sizes[0] / F_IN;        // 100000
    const int E = in_sizes[7];               // 1600000
    const int NB = (N + 255) / 256;          // 391
    const int R  = (N + RANGE - 1) / RANGE;  // 7
    const int chunk = (E + PCH - 1) / PCH;   // 50000

    char* ws = (char*)d_ws;
    float* h0   = (float*)ws; ws += (size_t)N * C * 4;
    float* ha   = (float*)ws; ws += (size_t)N * C * 4;
    float* hb   = (float*)ws; ws += (size_t)N * C * 4;
    int*   dego = (int*)ws;   ws += (size_t)N * 4;
    int*   degi = (int*)ws;   ws += (size_t)N * 4;
    float* ns   = (float*)ws; ws += (size_t)N * 4;
    float* nd   = (float*)ws; ws += (size_t)N * 4;
    int*   off  = (int*)ws;   ws += (size_t)N * 4;
    int*   bsum = (int*)ws;   ws += 512 * 4;
    int*   part = (int*)ws;   ws += (size_t)PCH * N * 4;
    unsigned long long* epack = (unsigned long long*)ws; ws += (size_t)E * 8;
    half8* B0 = (half8*)ws; ws += 4096 * 16;
    half8* B1 = (half8*)ws; ws += 2048 * 16;
    half8* B2 = (half8*)ws; ws += 256 * 16;

    // degrees via LDS histograms
    hist_k<<<PCH * R, 256, 0, stream>>>(src, part, N, E, R, chunk);
    colsum_k<<<NB, 256, 0, stream>>>(part, dego, N);
    hist_k<<<PCH * R, 256, 0, stream>>>(dst, part, N, E, R, chunk);
    colprefix_k<<<NB, 256, 0, stream>>>(part, degi, N);
    norm_kernel<<<NB, 256, 0, stream>>>(dego, degi, ns, nd, N);

    // CSR offsets + scatter
    scan1<<<NB, 256, 0, stream>>>(degi, off, bsum, N);
    scan2<<<1, 512, 0, stream>>>(bsum, NB);
    scan3<<<NB, 256, 0, stream>>>(off, bsum, N);
    scatter2_k<<<PCH * R, 256, 0, stream>>>(src, dst, ns, nd, off, part, epack, N, E, R, chunk);

    // MLP
    wpack<<<16, 256, 0, stream>>>(W0, B0, 256, 128);
    wpack<<<8, 256, 0, stream>>>(W1, B1, 128, 128);
    wpack<<<1, 256, 0, stream>>>(W2, B2, 128, 16);
    mlp_mfma<<<(N + 63) / 64, 256, 0, stream>>>(feat, B0, b0, B1, b1, B2, b2, h0, N);

    // propagation
    const float* cur = h0;
    for (int it = 0; it < KITER; ++it) {
        float* nxt = (it == KITER - 1) ? (float*)d_out : ((it & 1) ? hb : ha);
        gather4<<<(N * 4 + 255) / 256, 256, 0, stream>>>(epack, off, (const float4*)cur,
                                                         (const float4*)h0, (float4*)nxt, N, E);
        cur = nxt;
    }
}

// Round 4
// 529.203 us; speedup vs baseline: 2.3916x; 1.3326x over previous
//
#include <hip/hip_runtime.h>

typedef _Float16 half8 __attribute__((ext_vector_type(8)));
typedef _Float16 half4 __attribute__((ext_vector_type(4)));
typedef float f32x4 __attribute__((ext_vector_type(4)));
typedef unsigned short u16;
typedef unsigned long long u64;

constexpr int F_IN = 256;
constexpr int H    = 128;
constexpr int C    = 16;
constexpr int KITER = 10;

constexpr int RANGE = 32768;  // nodes per histogram range (16384 packed u32 words = 64 KB)
constexpr int PCH   = 128;    // edge chunks

// ---------------- packed-u16 LDS histogram (no global atomics) ----------------
// grid = PCH * R; block (p, r) counts idx in [r*RANGE, r*RANGE+RANGE) over chunk p.
// Two u16 counters per u32 word; counts <= chunk (12500) so halves never carry.

__global__ __launch_bounds__(256) void hist_k(const int* __restrict__ idx,
                                              u16* __restrict__ partial,
                                              int N, int E, int R, int chunk) {
    __shared__ unsigned int cnt[RANGE / 2];  // 64 KB
    const int p  = blockIdx.x / R;
    const int r  = blockIdx.x % R;
    const int lo = r * RANGE;
    const int hi = min(lo + RANGE, N);
    const int t  = threadIdx.x;
    for (int i = t; i < RANGE / 2; i += 256) cnt[i] = 0;
    __syncthreads();
    const int e0 = p * chunk, e1 = min(e0 + chunk, E);
    for (int e = e0 + t; e < e1; e += 256) {
        int d = idx[e];
        if (d >= lo && d < hi) {
            int dl = d - lo;
            atomicAdd(&cnt[dl >> 1], 1u << ((dl & 1) << 4));
        }
    }
    __syncthreads();
    for (int i = lo + t; i < hi; i += 256) {
        int il = i - lo;
        partial[(size_t)p * N + i] = (u16)(cnt[il >> 1] >> ((il & 1) << 4));
    }
}

// deg[i] = sum_p partial[p][i]
__global__ __launch_bounds__(256) void colsum_k(const u16* __restrict__ partial,
                                                int* __restrict__ deg, int N) {
    int i = blockIdx.x * 256 + threadIdx.x;
    if (i < N) {
        int s = 0;
#pragma unroll 8
        for (int p = 0; p < PCH; ++p) s += partial[(size_t)p * N + i];
        deg[i] = s;
    }
}

// in-place exclusive prefix along p; deg[i] = total
__global__ __launch_bounds__(256) void colprefix_k(u16* __restrict__ partial,
                                                   int* __restrict__ deg, int N) {
    int i = blockIdx.x * 256 + threadIdx.x;
    if (i < N) {
        int run = 0;
        for (int p = 0; p < PCH; ++p) {
            size_t q = (size_t)p * N + i;
            int v = partial[q];
            partial[q] = (u16)run;
            run += v;
        }
        deg[i] = run;
    }
}

__global__ __launch_bounds__(256) void norm_kernel(const int* __restrict__ deg_out,
                                                   const int* __restrict__ deg_in,
                                                   float* __restrict__ norm_src,
                                                   float* __restrict__ norm_dst, int N) {
    int i = blockIdx.x * 256 + threadIdx.x;
    if (i < N) {
        int a = deg_out[i];
        int b = deg_in[i];
        norm_src[i] = (a > 0) ? rsqrtf((float)a) : 0.0f;
        norm_dst[i] = (b > 0) ? rsqrtf((float)b) : 0.0f;
    }
}

// ---------------- scan for CSR offsets ----------------

__global__ __launch_bounds__(256) void scan1(const int* __restrict__ d, int* __restrict__ off,
                                             int* __restrict__ bsum, int N) {
    __shared__ int s[256];
    int t = threadIdx.x, i = blockIdx.x * 256 + t;
    int v = (i < N) ? d[i] : 0;
    s[t] = v;
    __syncthreads();
    for (int dd = 1; dd < 256; dd <<= 1) {
        int x = (t >= dd) ? s[t - dd] : 0;
        __syncthreads();
        s[t] += x;
        __syncthreads();
    }
    if (i < N) off[i] = s[t] - v;
    if (t == 255) bsum[blockIdx.x] = s[255];
}

__global__ __launch_bounds__(512) void scan2(int* __restrict__ bsum, int nb) {
    __shared__ int s[512];
    int t = threadIdx.x;
    int v = (t < nb) ? bsum[t] : 0;
    s[t] = v;
    __syncthreads();
    for (int dd = 1; dd < 512; dd <<= 1) {
        int x = (t >= dd) ? s[t - dd] : 0;
        __syncthreads();
        s[t] += x;
        __syncthreads();
    }
    if (t < nb) bsum[t] = s[t] - v;
}

__global__ __launch_bounds__(256) void scan3(int* __restrict__ off, const int* __restrict__ bsum,
                                             int N) {
    int i = blockIdx.x * 256 + threadIdx.x;
    if (i < N) off[i] += bsum[blockIdx.x];
}

// ---------------- CSR scatter (packed LDS ranks, no global atomics) ----------------

__global__ __launch_bounds__(256) void scatter2_k(const int* __restrict__ src,
                                                  const int* __restrict__ dst,
                                                  const float* __restrict__ ns,
                                                  const float* __restrict__ nd,
                                                  const int* __restrict__ off,
                                                  const u16* __restrict__ pprefix,
                                                  u64* __restrict__ epack,
                                                  int N, int E, int R, int chunk) {
    __shared__ unsigned int cnt[RANGE / 2];  // 64 KB
    const int p  = blockIdx.x / R;
    const int r  = blockIdx.x % R;
    const int lo = r * RANGE;
    const int hi = min(lo + RANGE, N);
    const int t  = threadIdx.x;
    for (int i = t; i < RANGE / 2; i += 256) cnt[i] = 0;
    __syncthreads();
    const int e0 = p * chunk, e1 = min(e0 + chunk, E);
    for (int e = e0 + t; e < e1; e += 256) {
        int d = dst[e];
        if (d >= lo && d < hi) {
            int dl    = d - lo;
            int shift = (dl & 1) << 4;
            unsigned int old = atomicAdd(&cnt[dl >> 1], 1u << shift);
            int rank = (int)((old >> shift) & 0xffffu);
            int s = src[e];
            float w = 0.9f * ns[s] * nd[d];
            int pos = off[d] + (int)pprefix[(size_t)p * N + d] + rank;
            epack[pos] = (u64)(unsigned int)s |
                         ((u64)__float_as_uint(w) << 32);
        }
    }
}

// ---------------- weight packing to MFMA fragment order ----------------

__global__ __launch_bounds__(256) void wpack(const float* __restrict__ W, half8* __restrict__ out,
                                             int K, int Ncols) {
    int tid = blockIdx.x * 256 + threadIdx.x;
    int KS = K / 32;
    int NT = Ncols / 16;
    int total = NT * KS * 64;
    if (tid < total) {
        int l  = tid & 63;
        int ks = (tid >> 6) % KS;
        int nt = tid / (KS * 64);
        int col = nt * 16 + (l & 15);
        int kb  = ks * 32 + ((l >> 4) * 8);
        half8 h;
#pragma unroll
        for (int j = 0; j < 8; ++j) h[j] = (_Float16)W[(kb + j) * Ncols + col];
        out[tid] = h;
    }
}

// ---------------- fused MLP via f16 MFMA ----------------

__global__ __launch_bounds__(256) void mlp_mfma(
    const float* __restrict__ feat,
    const half8* __restrict__ B0, const float* __restrict__ b0,
    const half8* __restrict__ B1, const float* __restrict__ b1,
    const half8* __restrict__ B2, const float* __restrict__ b2,
    float* __restrict__ hout, int N)
{
    __shared__ __align__(16) char lds[64 * 512 + 64 * 256];
    char* sA  = lds;             // f16[64][256] rows of 512B; later f16[64][128] H2
    char* sH1 = lds + 64 * 512;  // f16[64][128] rows of 256B

    const int t    = threadIdx.x;
    const int base = blockIdx.x * 64;
    const int l    = t & 63;
    const int w    = t >> 6;

    // ---- stage 64 feature rows as f16, swizzled ----
    {
        const float4* g4 = reinterpret_cast<const float4*>(feat);
        const int maxq = N * 64 - 1;
#pragma unroll
        for (int i = 0; i < 16; ++i) {
            int q = base * 64 + i * 256 + t;
            if (q > maxq) q = maxq;
            float4 a = g4[q];
            int lq   = i * 256 + t;
            int row  = lq >> 6;
            int colb = (lq & 63) * 8;
            int byte = row * 512 + (colb ^ ((row & 7) << 4));
            half4 h = {(_Float16)a.x, (_Float16)a.y, (_Float16)a.z, (_Float16)a.w};
            *reinterpret_cast<half4*>(sA + byte) = h;
        }
    }
    __syncthreads();

    const int arow = w * 16 + (l & 15);
    const f32x4 zero = {0.0f, 0.0f, 0.0f, 0.0f};

    // ---- layer 0: [16 rows x 256] @ [256 x 128] per wave ----
    f32x4 acc0[8];
#pragma unroll
    for (int nt = 0; nt < 8; ++nt) acc0[nt] = zero;
    for (int ks = 0; ks < 8; ++ks) {
        int byte = arow * 512 + (((ks * 64) + ((l >> 4) * 16)) ^ ((arow & 7) << 4));
        half8 a = *reinterpret_cast<const half8*>(sA + byte);
#pragma unroll
        for (int nt = 0; nt < 8; ++nt) {
            half8 b = B0[(nt * 8 + ks) * 64 + l];
            acc0[nt] = __builtin_amdgcn_mfma_f32_16x16x32_f16(a, b, acc0[nt], 0, 0, 0);
        }
    }
#pragma unroll
    for (int nt = 0; nt < 8; ++nt) {
        float bb = b0[nt * 16 + (l & 15)];
#pragma unroll
        for (int r = 0; r < 4; ++r) {
            int row  = w * 16 + (l >> 4) * 4 + r;
            int colb = (nt * 16 + (l & 15)) * 2;
            int byte = row * 256 + (colb ^ ((row & 7) << 4));
            *reinterpret_cast<_Float16*>(sH1 + byte) = (_Float16)fmaxf(acc0[nt][r] + bb, 0.0f);
        }
    }

    // ---- layer 1: [16 x 128] @ [128 x 128] ----
    f32x4 acc1[8];
#pragma unroll
    for (int nt = 0; nt < 8; ++nt) acc1[nt] = zero;
    for (int ks = 0; ks < 4; ++ks) {
        int byte = arow * 256 + (((ks * 64) + ((l >> 4) * 16)) ^ ((arow & 7) << 4));
        half8 a = *reinterpret_cast<const half8*>(sH1 + byte);
#pragma unroll
        for (int nt = 0; nt < 8; ++nt) {
            half8 b = B1[(nt * 4 + ks) * 64 + l];
            acc1[nt] = __builtin_amdgcn_mfma_f32_16x16x32_f16(a, b, acc1[nt], 0, 0, 0);
        }
    }

    __syncthreads();  // done reading sA -> reuse as H2

#pragma unroll
    for (int nt = 0; nt < 8; ++nt) {
        float bb = b1[nt * 16 + (l & 15)];
#pragma unroll
        for (int r = 0; r < 4; ++r) {
            int row  = w * 16 + (l >> 4) * 4 + r;
            int colb = (nt * 16 + (l & 15)) * 2;
            int byte = row * 256 + (colb ^ ((row & 7) << 4));
            *reinterpret_cast<_Float16*>(sA + byte) = (_Float16)fmaxf(acc1[nt][r] + bb, 0.0f);
        }
    }

    // ---- layer 2: [16 x 128] @ [128 x 16] ----
    f32x4 acc2 = zero;
    for (int ks = 0; ks < 4; ++ks) {
        int byte = arow * 256 + (((ks * 64) + ((l >> 4) * 16)) ^ ((arow & 7) << 4));
        half8 a = *reinterpret_cast<const half8*>(sA + byte);
        half8 b = B2[ks * 64 + l];
        acc2 = __builtin_amdgcn_mfma_f32_16x16x32_f16(a, b, acc2, 0, 0, 0);
    }
    {
        float bb = b2[l & 15];
#pragma unroll
        for (int r = 0; r < 4; ++r) {
            int row  = w * 16 + (l >> 4) * 4 + r;
            int node = base + row;
            if (node < N) hout[(size_t)node * C + (l & 15)] = acc2[r] + bb;
        }
    }
}

// ---------------- propagation: CSR gather, float4 channels, 2-way unrolled ----------------

__global__ __launch_bounds__(256) void gather4(const u64* __restrict__ ep,
                                               const int* __restrict__ off,
                                               const float4* __restrict__ hc,
                                               const float4* __restrict__ h0,
                                               float4* __restrict__ hn, int N, int E) {
    int gid = blockIdx.x * 256 + threadIdx.x;
    int node = gid >> 2;
    if (node >= N) return;
    int c = gid & 3;
    int o0 = off[node];
    int o1 = (node + 1 < N) ? off[node + 1] : E;
    float4 hv = h0[gid];
    float4 accA = {0.1f * hv.x, 0.1f * hv.y, 0.1f * hv.z, 0.1f * hv.w};
    float4 accB = {0.0f, 0.0f, 0.0f, 0.0f};
    int o = o0;
    for (; o + 2 <= o1; o += 2) {
        u64 v0 = ep[o];
        u64 v1 = ep[o + 1];
        int   s0 = (int)(unsigned int)v0;
        int   s1 = (int)(unsigned int)v1;
        float w0 = __uint_as_float((unsigned int)(v0 >> 32));
        float w1 = __uint_as_float((unsigned int)(v1 >> 32));
        float4 x0 = hc[s0 * 4 + c];
        float4 x1 = hc[s1 * 4 + c];
        accA.x = fmaf(w0, x0.x, accA.x);
        accA.y = fmaf(w0, x0.y, accA.y);
        accA.z = fmaf(w0, x0.z, accA.z);
        accA.w = fmaf(w0, x0.w, accA.w);
        accB.x = fmaf(w1, x1.x, accB.x);
        accB.y = fmaf(w1, x1.y, accB.y);
        accB.z = fmaf(w1, x1.z, accB.z);
        accB.w = fmaf(w1, x1.w, accB.w);
    }
    if (o < o1) {
        u64 v0 = ep[o];
        int   s0 = (int)(unsigned int)v0;
        float w0 = __uint_as_float((unsigned int)(v0 >> 32));
        float4 x0 = hc[s0 * 4 + c];
        accA.x = fmaf(w0, x0.x, accA.x);
        accA.y = fmaf(w0, x0.y, accA.y);
        accA.z = fmaf(w0, x0.z, accA.z);
        accA.w = fmaf(w0, x0.w, accA.w);
    }
    accA.x += accB.x; accA.y += accB.y; accA.z += accB.z; accA.w += accB.w;
    hn[gid] = accA;
}

// ---------------- launch ----------------

extern "C" void kernel_launch(void* const* d_in, const int* in_sizes, int n_in,
                              void* d_out, int out_size, void* d_ws, size_t ws_size,
                              hipStream_t stream) {
    const float* feat = (const float*)d_in[0];
    const float* W0   = (const float*)d_in[1];
    const float* b0   = (const float*)d_in[2];
    const float* W1   = (const float*)d_in[3];
    const float* b1   = (const float*)d_in[4];
    const float* W2   = (const float*)d_in[5];
    const float* b2   = (const float*)d_in[6];
    const int*   src  = (const int*)d_in[7];
    const int*   dst  = (const int*)d_in[8];

    const int N = in_sizes[0] / F_IN;        // 100000
    const int E = in_sizes[7];               // 1600000
    const int NB = (N + 255) / 256;          // 391
    const int R  = (N + RANGE - 1) / RANGE;  // 4
    const int chunk = (E + PCH - 1) / PCH;   // 12500 (< 65536: u16-safe)

    char* base = (char*)d_ws;
    // Region A: partial histogram (u16), dead after scatter2_k.
    u16* part = (u16*)base;                        // PCH*N*2 = 25.6 MB
    // Region B aliases region A: h buffers first written AFTER scatter2_k.
    float* h0 = (float*)base;                      // 6.4 MB
    float* ha = (float*)(base + (size_t)N * C * 4);        // 6.4 MB
    float* hb = (float*)(base + (size_t)N * C * 8);        // 6.4 MB
    char* ws = base + (size_t)PCH * N * 2;         // = 25.6 MB mark
    int*   dego = (int*)ws;   ws += (size_t)N * 4;
    int*   degi = (int*)ws;   ws += (size_t)N * 4;
    float* ns   = (float*)ws; ws += (size_t)N * 4;
    float* nd   = (float*)ws; ws += (size_t)N * 4;
    int*   off  = (int*)ws;   ws += (size_t)N * 4;
    int*   bsum = (int*)ws;   ws += 512 * 4;
    u64*   epack = (u64*)ws;  ws += (size_t)E * 8;
    half8* B0 = (half8*)ws;   ws += 4096 * 16;
    half8* B1 = (half8*)ws;   ws += 2048 * 16;
    half8* B2 = (half8*)ws;   ws += 256 * 16;

    // degrees via packed LDS histograms
    hist_k<<<PCH * R, 256, 0, stream>>>(src, part, N, E, R, chunk);
    colsum_k<<<NB, 256, 0, stream>>>(part, dego, N);
    hist_k<<<PCH * R, 256, 0, stream>>>(dst, part, N, E, R, chunk);
    colprefix_k<<<NB, 256, 0, stream>>>(part, degi, N);
    norm_kernel<<<NB, 256, 0, stream>>>(dego, degi, ns, nd, N);

    // CSR offsets + scatter
    scan1<<<NB, 256, 0, stream>>>(degi, off, bsum, N);
    scan2<<<1, 512, 0, stream>>>(bsum, NB);
    scan3<<<NB, 256, 0, stream>>>(off, bsum, N);
    scatter2_k<<<PCH * R, 256, 0, stream>>>(src, dst, ns, nd, off, part, epack, N, E, R, chunk);

    // MLP (h0 write happens after scatter2_k in stream order -> aliasing safe)
    wpack<<<16, 256, 0, stream>>>(W0, B0, 256, 128);
    wpack<<<8, 256, 0, stream>>>(W1, B1, 128, 128);
    wpack<<<1, 256, 0, stream>>>(W2, B2, 128, 16);
    mlp_mfma<<<(N + 63) / 64, 256, 0, stream>>>(feat, B0, b0, B1, b1, B2, b2, h0, N);

    // propagation
    const float* cur = h0;
    for (int it = 0; it < KITER; ++it) {
        float* nxt = (it == KITER - 1) ? (float*)d_out : ((it & 1) ? hb : ha);
        gather4<<<(N * 4 + 255) / 256, 256, 0, stream>>>(epack, off, (const float4*)cur,
                                                         (const float4*)h0, (float4*)nxt, N, E);
        cur = nxt;
    }
}

// Round 5
// 390.241 us; speedup vs baseline: 3.2432x; 1.3561x over previous
//
#include <hip/hip_runtime.h>

typedef _Float16 half8 __attribute__((ext_vector_type(8)));
typedef _Float16 half4 __attribute__((ext_vector_type(4)));
typedef float f32x4 __attribute__((ext_vector_type(4)));
typedef unsigned short u16;
typedef unsigned int u32;
typedef unsigned long long u64;

constexpr int F_IN = 256;
constexpr int H    = 128;
constexpr int C    = 16;
constexpr int KITER = 10;

constexpr int RANGE = 32768;  // nodes per histogram range (16384 packed u32 words = 64 KB)
constexpr int PCH   = 128;    // edge chunks

// ---------------- packed-u16 LDS histogram (no global atomics) ----------------

__global__ __launch_bounds__(256) void hist_k(const int* __restrict__ idx,
                                              u16* __restrict__ partial,
                                              int N, int E, int R, int chunk) {
    __shared__ unsigned int cnt[RANGE / 2];  // 64 KB
    const int p  = blockIdx.x / R;
    const int r  = blockIdx.x % R;
    const int lo = r * RANGE;
    const int hi = min(lo + RANGE, N);
    const int t  = threadIdx.x;
    for (int i = t; i < RANGE / 2; i += 256) cnt[i] = 0;
    __syncthreads();
    const int e0 = p * chunk, e1 = min(e0 + chunk, E);
    for (int e = e0 + t; e < e1; e += 256) {
        int d = idx[e];
        if (d >= lo && d < hi) {
            int dl = d - lo;
            atomicAdd(&cnt[dl >> 1], 1u << ((dl & 1) << 4));
        }
    }
    __syncthreads();
    for (int i = lo + t; i < hi; i += 256) {
        int il = i - lo;
        partial[(size_t)p * N + i] = (u16)(cnt[il >> 1] >> ((il & 1) << 4));
    }
}

__global__ __launch_bounds__(256) void colsum_k(const u16* __restrict__ partial,
                                                int* __restrict__ deg, int N) {
    int i = blockIdx.x * 256 + threadIdx.x;
    if (i < N) {
        int s = 0;
#pragma unroll 8
        for (int p = 0; p < PCH; ++p) s += partial[(size_t)p * N + i];
        deg[i] = s;
    }
}

__global__ __launch_bounds__(256) void colprefix_k(u16* __restrict__ partial,
                                                   int* __restrict__ deg, int N) {
    int i = blockIdx.x * 256 + threadIdx.x;
    if (i < N) {
        int run = 0;
        for (int p = 0; p < PCH; ++p) {
            size_t q = (size_t)p * N + i;
            int v = partial[q];
            partial[q] = (u16)run;
            run += v;
        }
        deg[i] = run;
    }
}

__global__ __launch_bounds__(256) void norm_kernel(const int* __restrict__ deg_out,
                                                   const int* __restrict__ deg_in,
                                                   float* __restrict__ norm_src,
                                                   float* __restrict__ norm_dst, int N) {
    int i = blockIdx.x * 256 + threadIdx.x;
    if (i < N) {
        int a = deg_out[i];
        int b = deg_in[i];
        norm_src[i] = (a > 0) ? rsqrtf((float)a) : 0.0f;
        norm_dst[i] = (b > 0) ? rsqrtf((float)b) : 0.0f;
    }
}

// ---------------- scan for CSR offsets ----------------

__global__ __launch_bounds__(256) void scan1(const int* __restrict__ d, int* __restrict__ off,
                                             int* __restrict__ bsum, int N) {
    __shared__ int s[256];
    int t = threadIdx.x, i = blockIdx.x * 256 + t;
    int v = (i < N) ? d[i] : 0;
    s[t] = v;
    __syncthreads();
    for (int dd = 1; dd < 256; dd <<= 1) {
        int x = (t >= dd) ? s[t - dd] : 0;
        __syncthreads();
        s[t] += x;
        __syncthreads();
    }
    if (i < N) off[i] = s[t] - v;
    if (t == 255) bsum[blockIdx.x] = s[255];
}

__global__ __launch_bounds__(512) void scan2(int* __restrict__ bsum, int nb) {
    __shared__ int s[512];
    int t = threadIdx.x;
    int v = (t < nb) ? bsum[t] : 0;
    s[t] = v;
    __syncthreads();
    for (int dd = 1; dd < 512; dd <<= 1) {
        int x = (t >= dd) ? s[t - dd] : 0;
        __syncthreads();
        s[t] += x;
        __syncthreads();
    }
    if (t < nb) bsum[t] = s[t] - v;
}

__global__ __launch_bounds__(256) void scan3(int* __restrict__ off, const int* __restrict__ bsum,
                                             int N) {
    int i = blockIdx.x * 256 + threadIdx.x;
    if (i < N) off[i] += bsum[blockIdx.x];
}

// ---------------- CSR scatter (packed LDS ranks; payload = src index only) ----------------

__global__ __launch_bounds__(256) void scatter2_k(const int* __restrict__ src,
                                                  const int* __restrict__ dst,
                                                  const int* __restrict__ off,
                                                  const u16* __restrict__ pprefix,
                                                  u32* __restrict__ epack,
                                                  int N, int E, int R, int chunk) {
    __shared__ unsigned int cnt[RANGE / 2];  // 64 KB
    const int p  = blockIdx.x / R;
    const int r  = blockIdx.x % R;
    const int lo = r * RANGE;
    const int hi = min(lo + RANGE, N);
    const int t  = threadIdx.x;
    for (int i = t; i < RANGE / 2; i += 256) cnt[i] = 0;
    __syncthreads();
    const int e0 = p * chunk, e1 = min(e0 + chunk, E);
    for (int e = e0 + t; e < e1; e += 256) {
        int d = dst[e];
        if (d >= lo && d < hi) {
            int dl    = d - lo;
            int shift = (dl & 1) << 4;
            unsigned int old = atomicAdd(&cnt[dl >> 1], 1u << shift);
            int rank = (int)((old >> shift) & 0xffffu);
            int pos = off[d] + (int)pprefix[(size_t)p * N + d] + rank;
            epack[pos] = (u32)src[e];
        }
    }
}

// ---------------- weight packing to MFMA fragment order ----------------

__global__ __launch_bounds__(256) void wpack(const float* __restrict__ W, half8* __restrict__ out,
                                             int K, int Ncols) {
    int tid = blockIdx.x * 256 + threadIdx.x;
    int KS = K / 32;
    int NT = Ncols / 16;
    int total = NT * KS * 64;
    if (tid < total) {
        int l  = tid & 63;
        int ks = (tid >> 6) % KS;
        int nt = tid / (KS * 64);
        int col = nt * 16 + (l & 15);
        int kb  = ks * 32 + ((l >> 4) * 8);
        half8 h;
#pragma unroll
        for (int j = 0; j < 8; ++j) h[j] = (_Float16)W[(kb + j) * Ncols + col];
        out[tid] = h;
    }
}

// ---------------- fused MLP via f16 MFMA: barrier-free, A in registers ----------------
// 4 waves/block, wave owns 16 rows end-to-end. H1/H2 in 8KB wave-private LDS.

__global__ __launch_bounds__(256, 2) void mlp_mfma(
    const float* __restrict__ feat,
    const half8* __restrict__ B0, const float* __restrict__ b0,
    const half8* __restrict__ B1, const float* __restrict__ b1,
    const half8* __restrict__ B2, const float* __restrict__ b2,
    const float* __restrict__ ns,
    float* __restrict__ h0out, _Float16* __restrict__ g0out, int N)
{
    __shared__ __align__(16) char lds[4 * 8192];
    const int t  = threadIdx.x;
    const int l  = t & 63;
    const int w  = t >> 6;
    const int cl = l & 15;   // A-row within wave tile / C-col within frag
    const int qk = l >> 4;
    char* swp = lds + w * 8192;  // H1 at +0, H2 at +4096 (wave-private)

    const int rowg = blockIdx.x * 64 + w * 16 + cl;
    const int rowc = (rowg < N) ? rowg : (N - 1);

    // ---- layer 0: A direct from global (16 independent dwordx4 loads) ----
    const float* ap = feat + (size_t)rowc * F_IN + qk * 8;
    half8 a0[8];
#pragma unroll
    for (int ks = 0; ks < 8; ++ks) {
        float4 f0 = *reinterpret_cast<const float4*>(ap + ks * 32);
        float4 f1 = *reinterpret_cast<const float4*>(ap + ks * 32 + 4);
        half8 h;
        h[0] = (_Float16)f0.x; h[1] = (_Float16)f0.y; h[2] = (_Float16)f0.z; h[3] = (_Float16)f0.w;
        h[4] = (_Float16)f1.x; h[5] = (_Float16)f1.y; h[6] = (_Float16)f1.z; h[7] = (_Float16)f1.w;
        a0[ks] = h;
    }
    f32x4 acc0[8];
#pragma unroll
    for (int nt = 0; nt < 8; ++nt) acc0[nt] = (f32x4){0.f, 0.f, 0.f, 0.f};
#pragma unroll
    for (int ks = 0; ks < 8; ++ks)
#pragma unroll
        for (int nt = 0; nt < 8; ++nt)
            acc0[nt] = __builtin_amdgcn_mfma_f32_16x16x32_f16(a0[ks], B0[(nt * 8 + ks) * 64 + l],
                                                              acc0[nt], 0, 0, 0);
    // bias+relu -> H1 (swizzled u16 stores)
#pragma unroll
    for (int nt = 0; nt < 8; ++nt) {
        float bb = b0[nt * 16 + cl];
#pragma unroll
        for (int r = 0; r < 4; ++r) {
            int orow = qk * 4 + r;
            int byte = orow * 256 + (((nt * 16 + cl) * 2) ^ ((orow & 7) << 4));
            *reinterpret_cast<_Float16*>(swp + byte) = (_Float16)fmaxf(acc0[nt][r] + bb, 0.0f);
        }
    }

    // ---- layer 1 ----
    half8 a1[4];
#pragma unroll
    for (int ks = 0; ks < 4; ++ks) {
        int byte = cl * 256 + (((qk * 8 + ks * 32) * 2) ^ ((cl & 7) << 4));
        a1[ks] = *reinterpret_cast<const half8*>(swp + byte);
    }
    f32x4 acc1[8];
#pragma unroll
    for (int nt = 0; nt < 8; ++nt) acc1[nt] = (f32x4){0.f, 0.f, 0.f, 0.f};
#pragma unroll
    for (int ks = 0; ks < 4; ++ks)
#pragma unroll
        for (int nt = 0; nt < 8; ++nt)
            acc1[nt] = __builtin_amdgcn_mfma_f32_16x16x32_f16(a1[ks], B1[(nt * 4 + ks) * 64 + l],
                                                              acc1[nt], 0, 0, 0);
    // bias+relu -> H2 (second half of wave buffer)
#pragma unroll
    for (int nt = 0; nt < 8; ++nt) {
        float bb = b1[nt * 16 + cl];
#pragma unroll
        for (int r = 0; r < 4; ++r) {
            int orow = qk * 4 + r;
            int byte = 4096 + orow * 256 + (((nt * 16 + cl) * 2) ^ ((orow & 7) << 4));
            *reinterpret_cast<_Float16*>(swp + byte) = (_Float16)fmaxf(acc1[nt][r] + bb, 0.0f);
        }
    }

    // ---- layer 2 ----
    f32x4 acc2 = (f32x4){0.f, 0.f, 0.f, 0.f};
#pragma unroll
    for (int ks = 0; ks < 4; ++ks) {
        int byte = 4096 + cl * 256 + (((qk * 8 + ks * 32) * 2) ^ ((cl & 7) << 4));
        half8 a2 = *reinterpret_cast<const half8*>(swp + byte);
        acc2 = __builtin_amdgcn_mfma_f32_16x16x32_f16(a2, B2[ks * 64 + l], acc2, 0, 0, 0);
    }
    float bb2 = b2[cl];
#pragma unroll
    for (int r = 0; r < 4; ++r) {
        int orow = qk * 4 + r;
        int node = blockIdx.x * 64 + w * 16 + orow;
        if (node < N) {
            float hv = acc2[r] + bb2;
            h0out[(size_t)node * C + cl] = hv;
            g0out[(size_t)node * C + cl] = (_Float16)(hv * ns[node]);
        }
    }
}

// ---------------- propagation: gather of pre-scaled f16 g, norm hoisted ----------------

__global__ __launch_bounds__(256) void gatherg(const u32* __restrict__ ep,
                                               const int* __restrict__ off,
                                               const half4* __restrict__ g,
                                               const float4* __restrict__ h0,
                                               const float* __restrict__ ns,
                                               const float* __restrict__ nd,
                                               half4* __restrict__ gnext,
                                               float4* __restrict__ hout,
                                               int N, int E, int last) {
    int gid = blockIdx.x * 256 + threadIdx.x;
    int node = gid >> 2;
    if (node >= N) return;
    int c = gid & 3;
    int o0 = off[node];
    int o1 = (node + 1 < N) ? off[node + 1] : E;
    float4 aA = {0.f, 0.f, 0.f, 0.f};
    float4 aB = {0.f, 0.f, 0.f, 0.f};
    int o = o0;
    for (; o + 2 <= o1; o += 2) {
        int s0 = (int)ep[o];
        int s1 = (int)ep[o + 1];
        half4 x0 = g[s0 * 4 + c];
        half4 x1 = g[s1 * 4 + c];
        aA.x += (float)x0[0]; aA.y += (float)x0[1]; aA.z += (float)x0[2]; aA.w += (float)x0[3];
        aB.x += (float)x1[0]; aB.y += (float)x1[1]; aB.z += (float)x1[2]; aB.w += (float)x1[3];
    }
    if (o < o1) {
        int s0 = (int)ep[o];
        half4 x0 = g[s0 * 4 + c];
        aA.x += (float)x0[0]; aA.y += (float)x0[1]; aA.z += (float)x0[2]; aA.w += (float)x0[3];
    }
    float k = 0.9f * nd[node];
    float4 hv = h0[gid];
    float4 res;
    res.x = fmaf(k, aA.x + aB.x, 0.1f * hv.x);
    res.y = fmaf(k, aA.y + aB.y, 0.1f * hv.y);
    res.z = fmaf(k, aA.z + aB.z, 0.1f * hv.z);
    res.w = fmaf(k, aA.w + aB.w, 0.1f * hv.w);
    if (last) {
        hout[gid] = res;
    } else {
        float s = ns[node];
        half4 gv;
        gv[0] = (_Float16)(res.x * s);
        gv[1] = (_Float16)(res.y * s);
        gv[2] = (_Float16)(res.z * s);
        gv[3] = (_Float16)(res.w * s);
        gnext[gid] = gv;
    }
}

// ---------------- launch ----------------

extern "C" void kernel_launch(void* const* d_in, const int* in_sizes, int n_in,
                              void* d_out, int out_size, void* d_ws, size_t ws_size,
                              hipStream_t stream) {
    const float* feat = (const float*)d_in[0];
    const float* W0   = (const float*)d_in[1];
    const float* b0   = (const float*)d_in[2];
    const float* W1   = (const float*)d_in[3];
    const float* b1   = (const float*)d_in[4];
    const float* W2   = (const float*)d_in[5];
    const float* b2   = (const float*)d_in[6];
    const int*   src  = (const int*)d_in[7];
    const int*   dst  = (const int*)d_in[8];

    const int N = in_sizes[0] / F_IN;        // 100000
    const int E = in_sizes[7];               // 1600000
    const int NB = (N + 255) / 256;          // 391
    const int R  = (N + RANGE - 1) / RANGE;  // 4
    const int chunk = (E + PCH - 1) / PCH;   // 12500 (< 65536: u16-safe)

    char* base = (char*)d_ws;
    // Region A: partial histogram (u16, 25.6 MB), dead after scatter2_k.
    u16* part = (u16*)base;
    // Region B aliases A: h/g buffers first written AFTER scatter2_k.
    float*    h0 = (float*)base;                                  // 6.4 MB
    _Float16* g0 = (_Float16*)(base + (size_t)N * C * 4);         // 3.2 MB
    _Float16* ga = (_Float16*)(base + (size_t)N * C * 6);         // 3.2 MB
    _Float16* gb = (_Float16*)(base + (size_t)N * C * 8);         // 3.2 MB
    char* ws = base + (size_t)PCH * N * 2;   // = 25.6 MB mark
    int*   dego = (int*)ws;   ws += (size_t)N * 4;
    int*   degi = (int*)ws;   ws += (size_t)N * 4;
    float* ns   = (float*)ws; ws += (size_t)N * 4;
    float* nd   = (float*)ws; ws += (size_t)N * 4;
    int*   off  = (int*)ws;   ws += (size_t)N * 4;
    int*   bsum = (int*)ws;   ws += 512 * 4;
    u32*   epack = (u32*)ws;  ws += (size_t)E * 4;
    half8* B0 = (half8*)ws;   ws += 4096 * 16;
    half8* B1 = (half8*)ws;   ws += 2048 * 16;
    half8* B2 = (half8*)ws;   ws += 256 * 16;

    // degrees via packed LDS histograms
    hist_k<<<PCH * R, 256, 0, stream>>>(src, part, N, E, R, chunk);
    colsum_k<<<NB, 256, 0, stream>>>(part, dego, N);
    hist_k<<<PCH * R, 256, 0, stream>>>(dst, part, N, E, R, chunk);
    colprefix_k<<<NB, 256, 0, stream>>>(part, degi, N);
    norm_kernel<<<NB, 256, 0, stream>>>(dego, degi, ns, nd, N);

    // CSR offsets + scatter (src-only payload)
    scan1<<<NB, 256, 0, stream>>>(degi, off, bsum, N);
    scan2<<<1, 512, 0, stream>>>(bsum, NB);
    scan3<<<NB, 256, 0, stream>>>(off, bsum, N);
    scatter2_k<<<PCH * R, 256, 0, stream>>>(src, dst, off, part, epack, N, E, R, chunk);

    // MLP (writes h0 and g0 = ns*h0; runs after scatter -> aliasing safe)
    wpack<<<16, 256, 0, stream>>>(W0, B0, 256, 128);
    wpack<<<8, 256, 0, stream>>>(W1, B1, 128, 128);
    wpack<<<1, 256, 0, stream>>>(W2, B2, 128, 16);
    mlp_mfma<<<(N + 63) / 64, 256, 0, stream>>>(feat, B0, b0, B1, b1, B2, b2, ns, h0, g0, N);

    // propagation
    const _Float16* curg = g0;
    for (int it = 0; it < KITER; ++it) {
        int last = (it == KITER - 1);
        _Float16* nxtg = (it & 1) ? gb : ga;
        gatherg<<<(N * 4 + 255) / 256, 256, 0, stream>>>(epack, off, (const half4*)curg,
                                                         (const float4*)h0, ns, nd,
                                                         (half4*)nxtg, (float4*)d_out, N, E, last);
        curg = nxtg;
    }
}

// Round 6
// 367.966 us; speedup vs baseline: 3.4395x; 1.0605x over previous
//
#include <hip/hip_runtime.h>

typedef _Float16 half8 __attribute__((ext_vector_type(8)));
typedef _Float16 half4 __attribute__((ext_vector_type(4)));
typedef float f32x4 __attribute__((ext_vector_type(4)));
typedef unsigned short u16;
typedef unsigned int u32;

constexpr int F_IN = 256;
constexpr int H    = 128;
constexpr int C    = 16;
constexpr int KITER = 10;

constexpr int RANGE = 16384;  // nodes per histogram range (8192 packed u32 words = 32 KB)
constexpr int PCH   = 128;    // edge chunks

// ---------------- packed-u16 LDS histogram (no global atomics) ----------------

__global__ __launch_bounds__(256) void hist_k(const int* __restrict__ idx,
                                              u16* __restrict__ partial,
                                              int N, int E, int R, int chunk) {
    __shared__ unsigned int cnt[RANGE / 2];  // 32 KB
    const int p  = blockIdx.x / R;
    const int r  = blockIdx.x % R;
    const int lo = r * RANGE;
    const int hi = min(lo + RANGE, N);
    const int t  = threadIdx.x;
    for (int i = t; i < RANGE / 2; i += 256) cnt[i] = 0;
    __syncthreads();
    const int e0 = p * chunk, e1 = min(e0 + chunk, E);
    for (int e = e0 + t; e < e1; e += 256) {
        int d = idx[e];
        if (d >= lo && d < hi) {
            int dl = d - lo;
            atomicAdd(&cnt[dl >> 1], 1u << ((dl & 1) << 4));
        }
    }
    __syncthreads();
    for (int i = lo + t; i < hi; i += 256) {
        int il = i - lo;
        partial[(size_t)p * N + i] = (u16)(cnt[il >> 1] >> ((il & 1) << 4));
    }
}

__global__ __launch_bounds__(256) void colsum_k(const u16* __restrict__ partial,
                                                int* __restrict__ deg, int N) {
    int i = blockIdx.x * 256 + threadIdx.x;
    if (i < N) {
        int s = 0;
#pragma unroll 8
        for (int p = 0; p < PCH; ++p) s += partial[(size_t)p * N + i];
        deg[i] = s;
    }
}

// exclusive prefix along p over dst-partial; also emits degi, ns, nd
__global__ __launch_bounds__(256) void colprefix_norm_k(u16* __restrict__ partial,
                                                        const int* __restrict__ dego,
                                                        int* __restrict__ degi,
                                                        float* __restrict__ ns,
                                                        float* __restrict__ nd, int N) {
    int i = blockIdx.x * 256 + threadIdx.x;
    if (i < N) {
        int run = 0;
        for (int p = 0; p < PCH; ++p) {
            size_t q = (size_t)p * N + i;
            int v = partial[q];
            partial[q] = (u16)run;
            run += v;
        }
        degi[i] = run;
        int a = dego[i];
        ns[i] = (a > 0) ? rsqrtf((float)a) : 0.0f;
        nd[i] = (run > 0) ? rsqrtf((float)run) : 0.0f;
    }
}

// ---------------- scan for CSR offsets ----------------

__global__ __launch_bounds__(256) void scan1(const int* __restrict__ d, int* __restrict__ off,
                                             int* __restrict__ bsum, int N) {
    __shared__ int s[256];
    int t = threadIdx.x, i = blockIdx.x * 256 + t;
    int v = (i < N) ? d[i] : 0;
    s[t] = v;
    __syncthreads();
    for (int dd = 1; dd < 256; dd <<= 1) {
        int x = (t >= dd) ? s[t - dd] : 0;
        __syncthreads();
        s[t] += x;
        __syncthreads();
    }
    if (i < N) off[i] = s[t] - v;
    if (t == 255) bsum[blockIdx.x] = s[255];
}

__global__ __launch_bounds__(512) void scan2(int* __restrict__ bsum, int nb) {
    __shared__ int s[512];
    int t = threadIdx.x;
    int v = (t < nb) ? bsum[t] : 0;
    s[t] = v;
    __syncthreads();
    for (int dd = 1; dd < 512; dd <<= 1) {
        int x = (t >= dd) ? s[t - dd] : 0;
        __syncthreads();
        s[t] += x;
        __syncthreads();
    }
    if (t < nb) bsum[t] = s[t] - v;
}

__global__ __launch_bounds__(256) void scan3(int* __restrict__ off, const int* __restrict__ bsum,
                                             int N) {
    int i = blockIdx.x * 256 + threadIdx.x;
    if (i < N) off[i] += bsum[blockIdx.x];
}

// ---------------- CSR scatter (packed LDS ranks; payload = src index only) ----------------

__global__ __launch_bounds__(256) void scatter2_k(const int* __restrict__ src,
                                                  const int* __restrict__ dst,
                                                  const int* __restrict__ off,
                                                  const u16* __restrict__ pprefix,
                                                  u32* __restrict__ epack,
                                                  int N, int E, int R, int chunk) {
    __shared__ unsigned int cnt[RANGE / 2];  // 32 KB
    const int p  = blockIdx.x / R;
    const int r  = blockIdx.x % R;
    const int lo = r * RANGE;
    const int hi = min(lo + RANGE, N);
    const int t  = threadIdx.x;
    for (int i = t; i < RANGE / 2; i += 256) cnt[i] = 0;
    __syncthreads();
    const int e0 = p * chunk, e1 = min(e0 + chunk, E);
    for (int e = e0 + t; e < e1; e += 256) {
        int d = dst[e];
        if (d >= lo && d < hi) {
            int dl    = d - lo;
            int shift = (dl & 1) << 4;
            unsigned int old = atomicAdd(&cnt[dl >> 1], 1u << shift);
            int rank = (int)((old >> shift) & 0xffffu);
            int pos = off[d] + (int)pprefix[(size_t)p * N + d] + rank;
            epack[pos] = (u32)src[e];
        }
    }
}

// ---------------- weight packing: B[(ks*NT + nt)*64 + l][j] ----------------
// = (f16) W[ ks*32 + (l>>4)*8 + j ][ nt*16 + (l&15) ]  (nt contiguous inner)

__global__ __launch_bounds__(256) void wpack(const float* __restrict__ W, half8* __restrict__ out,
                                             int K, int Ncols) {
    int tid = blockIdx.x * 256 + threadIdx.x;
    int KS = K / 32;
    int NT = Ncols / 16;
    int total = NT * KS * 64;
    if (tid < total) {
        int l  = tid & 63;
        int q  = tid >> 6;
        int nt = q % NT;
        int ks = q / NT;
        int col = nt * 16 + (l & 15);
        int kb  = ks * 32 + ((l >> 4) * 8);
        half8 h;
#pragma unroll
        for (int j = 0; j < 8; ++j) h[j] = (_Float16)W[(kb + j) * Ncols + col];
        out[tid] = h;
    }
}

// ---------------- fused MLP via f16 MFMA: barrier-free, A in registers ----------------
// 4 waves/block, wave owns 16 rows end-to-end. ONE 4KB wave-private LDS buffer
// reused H1 -> H2 (a1 frags fully in regs before H2 stores; DS in-order per wave).

__global__ __launch_bounds__(256, 4) void mlp_mfma(
    const float* __restrict__ feat,
    const half8* __restrict__ B0, const float* __restrict__ b0,
    const half8* __restrict__ B1, const float* __restrict__ b1,
    const half8* __restrict__ B2, const float* __restrict__ b2,
    const float* __restrict__ ns,
    float* __restrict__ h0out, _Float16* __restrict__ g0out, int N)
{
    __shared__ __align__(16) char lds[4 * 4096];
    const int t  = threadIdx.x;
    const int l  = t & 63;
    const int w  = t >> 6;
    const int cl = l & 15;
    const int qk = l >> 4;
    char* swp = lds + w * 4096;  // wave-private H buffer

    const int rowg = blockIdx.x * 64 + w * 16 + cl;
    const int rowc = (rowg < N) ? rowg : (N - 1);

    // ---- layer 0: A direct from global (16 independent dwordx4 loads) ----
    const float* ap = feat + (size_t)rowc * F_IN + qk * 8;
    half8 a0[8];
#pragma unroll
    for (int ks = 0; ks < 8; ++ks) {
        float4 f0 = *reinterpret_cast<const float4*>(ap + ks * 32);
        float4 f1 = *reinterpret_cast<const float4*>(ap + ks * 32 + 4);
        half8 h;
        h[0] = (_Float16)f0.x; h[1] = (_Float16)f0.y; h[2] = (_Float16)f0.z; h[3] = (_Float16)f0.w;
        h[4] = (_Float16)f1.x; h[5] = (_Float16)f1.y; h[6] = (_Float16)f1.z; h[7] = (_Float16)f1.w;
        a0[ks] = h;
    }
    f32x4 acc0[8];
#pragma unroll
    for (int nt = 0; nt < 8; ++nt) acc0[nt] = (f32x4){0.f, 0.f, 0.f, 0.f};
#pragma unroll
    for (int ks = 0; ks < 8; ++ks)
#pragma unroll
        for (int nt = 0; nt < 8; ++nt)
            acc0[nt] = __builtin_amdgcn_mfma_f32_16x16x32_f16(a0[ks], B0[(ks * 8 + nt) * 64 + l],
                                                              acc0[nt], 0, 0, 0);
    // bias+relu -> H1 (swizzled u16 stores)
#pragma unroll
    for (int nt = 0; nt < 8; ++nt) {
        float bb = b0[nt * 16 + cl];
#pragma unroll
        for (int r = 0; r < 4; ++r) {
            int orow = qk * 4 + r;
            int byte = orow * 256 + (((nt * 16 + cl) * 2) ^ ((orow & 7) << 4));
            *reinterpret_cast<_Float16*>(swp + byte) = (_Float16)fmaxf(acc0[nt][r] + bb, 0.0f);
        }
    }

    // ---- layer 1: read ALL H1 frags to regs, then overwrite buffer with H2 ----
    half8 a1[4];
#pragma unroll
    for (int ks = 0; ks < 4; ++ks) {
        int byte = cl * 256 + (((qk * 8 + ks * 32) * 2) ^ ((cl & 7) << 4));
        a1[ks] = *reinterpret_cast<const half8*>(swp + byte);
    }
    f32x4 acc1[8];
#pragma unroll
    for (int nt = 0; nt < 8; ++nt) acc1[nt] = (f32x4){0.f, 0.f, 0.f, 0.f};
#pragma unroll
    for (int ks = 0; ks < 4; ++ks)
#pragma unroll
        for (int nt = 0; nt < 8; ++nt)
            acc1[nt] = __builtin_amdgcn_mfma_f32_16x16x32_f16(a1[ks], B1[(ks * 8 + nt) * 64 + l],
                                                              acc1[nt], 0, 0, 0);
    // bias+relu -> H2 (same 4KB buffer; wave-private, DS in-order)
#pragma unroll
    for (int nt = 0; nt < 8; ++nt) {
        float bb = b1[nt * 16 + cl];
#pragma unroll
        for (int r = 0; r < 4; ++r) {
            int orow = qk * 4 + r;
            int byte = orow * 256 + (((nt * 16 + cl) * 2) ^ ((orow & 7) << 4));
            *reinterpret_cast<_Float16*>(swp + byte) = (_Float16)fmaxf(acc1[nt][r] + bb, 0.0f);
        }
    }

    // ---- layer 2 ----
    f32x4 acc2 = (f32x4){0.f, 0.f, 0.f, 0.f};
#pragma unroll
    for (int ks = 0; ks < 4; ++ks) {
        int byte = cl * 256 + (((qk * 8 + ks * 32) * 2) ^ ((cl & 7) << 4));
        half8 a2 = *reinterpret_cast<const half8*>(swp + byte);
        acc2 = __builtin_amdgcn_mfma_f32_16x16x32_f16(a2, B2[ks * 64 + l], acc2, 0, 0, 0);
    }
    float bb2 = b2[cl];
#pragma unroll
    for (int r = 0; r < 4; ++r) {
        int orow = qk * 4 + r;
        int node = blockIdx.x * 64 + w * 16 + orow;
        if (node < N) {
            float hv = acc2[r] + bb2;
            h0out[(size_t)node * C + cl] = hv;
            g0out[(size_t)node * C + cl] = (_Float16)(hv * ns[node]);
        }
    }
}

// ---------------- propagation: gather of pre-scaled f16 g, unroll-4 ----------------

__global__ __launch_bounds__(256) void gatherg(const u32* __restrict__ ep,
                                               const int* __restrict__ off,
                                               const half4* __restrict__ g,
                                               const float4* __restrict__ h0,
                                               const float* __restrict__ ns,
                                               const float* __restrict__ nd,
                                               half4* __restrict__ gnext,
                                               float4* __restrict__ hout,
                                               int N, int E, int last) {
    int gid = blockIdx.x * 256 + threadIdx.x;
    int node = gid >> 2;
    if (node >= N) return;
    int c = gid & 3;
    int o0 = off[node];
    int o1 = (node + 1 < N) ? off[node + 1] : E;
    float4 aA = {0.f, 0.f, 0.f, 0.f};
    float4 aB = {0.f, 0.f, 0.f, 0.f};
    float4 aC = {0.f, 0.f, 0.f, 0.f};
    float4 aD = {0.f, 0.f, 0.f, 0.f};
    int o = o0;
    for (; o + 4 <= o1; o += 4) {
        int s0 = (int)ep[o];
        int s1 = (int)ep[o + 1];
        int s2 = (int)ep[o + 2];
        int s3 = (int)ep[o + 3];
        half4 x0 = g[s0 * 4 + c];
        half4 x1 = g[s1 * 4 + c];
        half4 x2 = g[s2 * 4 + c];
        half4 x3 = g[s3 * 4 + c];
        aA.x += (float)x0[0]; aA.y += (float)x0[1]; aA.z += (float)x0[2]; aA.w += (float)x0[3];
        aB.x += (float)x1[0]; aB.y += (float)x1[1]; aB.z += (float)x1[2]; aB.w += (float)x1[3];
        aC.x += (float)x2[0]; aC.y += (float)x2[1]; aC.z += (float)x2[2]; aC.w += (float)x2[3];
        aD.x += (float)x3[0]; aD.y += (float)x3[1]; aD.z += (float)x3[2]; aD.w += (float)x3[3];
    }
    for (; o < o1; ++o) {
        int s0 = (int)ep[o];
        half4 x0 = g[s0 * 4 + c];
        aA.x += (float)x0[0]; aA.y += (float)x0[1]; aA.z += (float)x0[2]; aA.w += (float)x0[3];
    }
    aA.x += aB.x + aC.x + aD.x;
    aA.y += aB.y + aC.y + aD.y;
    aA.z += aB.z + aC.z + aD.z;
    aA.w += aB.w + aC.w + aD.w;
    float k = 0.9f * nd[node];
    float4 hv = h0[gid];
    float4 res;
    res.x = fmaf(k, aA.x, 0.1f * hv.x);
    res.y = fmaf(k, aA.y, 0.1f * hv.y);
    res.z = fmaf(k, aA.z, 0.1f * hv.z);
    res.w = fmaf(k, aA.w, 0.1f * hv.w);
    if (last) {
        hout[gid] = res;
    } else {
        float s = ns[node];
        half4 gv;
        gv[0] = (_Float16)(res.x * s);
        gv[1] = (_Float16)(res.y * s);
        gv[2] = (_Float16)(res.z * s);
        gv[3] = (_Float16)(res.w * s);
        gnext[gid] = gv;
    }
}

// ---------------- launch ----------------

extern "C" void kernel_launch(void* const* d_in, const int* in_sizes, int n_in,
                              void* d_out, int out_size, void* d_ws, size_t ws_size,
                              hipStream_t stream) {
    const float* feat = (const float*)d_in[0];
    const float* W0   = (const float*)d_in[1];
    const float* b0   = (const float*)d_in[2];
    const float* W1   = (const float*)d_in[3];
    const float* b1   = (const float*)d_in[4];
    const float* W2   = (const float*)d_in[5];
    const float* b2   = (const float*)d_in[6];
    const int*   src  = (const int*)d_in[7];
    const int*   dst  = (const int*)d_in[8];

    const int N = in_sizes[0] / F_IN;        // 100000
    const int E = in_sizes[7];               // 1600000
    const int NB = (N + 255) / 256;          // 391
    const int R  = (N + RANGE - 1) / RANGE;  // 7
    const int chunk = (E + PCH - 1) / PCH;   // 12500 (< 32768: u16-safe per chunk)

    char* base = (char*)d_ws;
    // Region A: partial histogram (u16, 25.6 MB), dead after scatter2_k.
    u16* part = (u16*)base;
    // Region B aliases A: h/g buffers first written AFTER scatter2_k.
    float*    h0 = (float*)base;                                  // 6.4 MB
    _Float16* g0 = (_Float16*)(base + (size_t)N * C * 4);         // 3.2 MB
    _Float16* ga = (_Float16*)(base + (size_t)N * C * 6);         // 3.2 MB
    _Float16* gb = (_Float16*)(base + (size_t)N * C * 8);         // 3.2 MB
    char* ws = base + (size_t)PCH * N * 2;   // = 25.6 MB mark
    int*   dego = (int*)ws;   ws += (size_t)N * 4;
    int*   degi = (int*)ws;   ws += (size_t)N * 4;
    float* ns   = (float*)ws; ws += (size_t)N * 4;
    float* nd   = (float*)ws; ws += (size_t)N * 4;
    int*   off  = (int*)ws;   ws += (size_t)N * 4;
    int*   bsum = (int*)ws;   ws += 512 * 4;
    u32*   epack = (u32*)ws;  ws += (size_t)E * 4;
    half8* B0 = (half8*)ws;   ws += 4096 * 16;
    half8* B1 = (half8*)ws;   ws += 2048 * 16;
    half8* B2 = (half8*)ws;   ws += 256 * 16;

    // degrees via packed LDS histograms
    hist_k<<<PCH * R, 256, 0, stream>>>(src, part, N, E, R, chunk);
    colsum_k<<<NB, 256, 0, stream>>>(part, dego, N);
    hist_k<<<PCH * R, 256, 0, stream>>>(dst, part, N, E, R, chunk);
    colprefix_norm_k<<<NB, 256, 0, stream>>>(part, dego, degi, ns, nd, N);

    // CSR offsets + scatter (src-only payload)
    scan1<<<NB, 256, 0, stream>>>(degi, off, bsum, N);
    scan2<<<1, 512, 0, stream>>>(bsum, NB);
    scan3<<<NB, 256, 0, stream>>>(off, bsum, N);
    scatter2_k<<<PCH * R, 256, 0, stream>>>(src, dst, off, part, epack, N, E, R, chunk);

    // MLP (writes h0 and g0 = ns*h0; runs after scatter -> aliasing safe)
    wpack<<<16, 256, 0, stream>>>(W0, B0, 256, 128);
    wpack<<<8, 256, 0, stream>>>(W1, B1, 128, 128);
    wpack<<<1, 256, 0, stream>>>(W2, B2, 128, 16);
    mlp_mfma<<<(N + 63) / 64, 256, 0, stream>>>(feat, B0, b0, B1, b1, B2, b2, ns, h0, g0, N);

    // propagation
    const _Float16* curg = g0;
    for (int it = 0; it < KITER; ++it) {
        int last = (it == KITER - 1);
        _Float16* nxtg = (it & 1) ? gb : ga;
        gatherg<<<(N * 4 + 255) / 256, 256, 0, stream>>>(epack, off, (const half4*)curg,
                                                         (const float4*)h0, ns, nd,
                                                         (half4*)nxtg, (float4*)d_out, N, E, last);
        curg = nxtg;
    }
}

// Round 7
// 345.221 us; speedup vs baseline: 3.6662x; 1.0659x over previous
//
#include <hip/hip_runtime.h>

typedef _Float16 half8 __attribute__((ext_vector_type(8)));
typedef _Float16 half4 __attribute__((ext_vector_type(4)));
typedef float f32x4 __attribute__((ext_vector_type(4)));
typedef unsigned short u16;
typedef unsigned int u32;

constexpr int F_IN = 256;
constexpr int H    = 128;
constexpr int C    = 16;
constexpr int KITER = 10;

constexpr int RANGE = 16384;  // nodes per histogram range (8192 packed u32 words = 32 KB)
constexpr int PCH   = 128;    // edge chunks

// ---------------- packed-u16 LDS histogram (no global atomics) ----------------

__global__ __launch_bounds__(256) void hist_k(const int* __restrict__ idx,
                                              u16* __restrict__ partial,
                                              int N, int E, int R, int chunk) {
    __shared__ unsigned int cnt[RANGE / 2];  // 32 KB
    const int p  = blockIdx.x / R;
    const int r  = blockIdx.x % R;
    const int lo = r * RANGE;
    const int hi = min(lo + RANGE, N);
    const int t  = threadIdx.x;
    for (int i = t; i < RANGE / 2; i += 256) cnt[i] = 0;
    __syncthreads();
    const int e0 = p * chunk, e1 = min(e0 + chunk, E);
    for (int e = e0 + t; e < e1; e += 256) {
        int d = idx[e];
        if (d >= lo && d < hi) {
            int dl = d - lo;
            atomicAdd(&cnt[dl >> 1], 1u << ((dl & 1) << 4));
        }
    }
    __syncthreads();
    for (int i = lo + t; i < hi; i += 256) {
        int il = i - lo;
        partial[(size_t)p * N + i] = (u16)(cnt[il >> 1] >> ((il & 1) << 4));
    }
}

// dst-hist that ALSO records each edge's rank within (chunk p, node d).
__global__ __launch_bounds__(256) void hist_rank_k(const int* __restrict__ idx,
                                                   u16* __restrict__ partial,
                                                   u16* __restrict__ rank16,
                                                   int N, int E, int R, int chunk) {
    __shared__ unsigned int cnt[RANGE / 2];  // 32 KB
    const int p  = blockIdx.x / R;
    const int r  = blockIdx.x % R;
    const int lo = r * RANGE;
    const int hi = min(lo + RANGE, N);
    const int t  = threadIdx.x;
    for (int i = t; i < RANGE / 2; i += 256) cnt[i] = 0;
    __syncthreads();
    const int e0 = p * chunk, e1 = min(e0 + chunk, E);
    for (int e = e0 + t; e < e1; e += 256) {
        int d = idx[e];
        if (d >= lo && d < hi) {
            int dl    = d - lo;
            int shift = (dl & 1) << 4;
            unsigned int old = atomicAdd(&cnt[dl >> 1], 1u << shift);
            rank16[e] = (u16)((old >> shift) & 0xffffu);
        }
    }
    __syncthreads();
    for (int i = lo + t; i < hi; i += 256) {
        int il = i - lo;
        partial[(size_t)p * N + i] = (u16)(cnt[il >> 1] >> ((il & 1) << 4));
    }
}

__global__ __launch_bounds__(256) void colsum_k(const u16* __restrict__ partial,
                                                int* __restrict__ deg, int N) {
    int i = blockIdx.x * 256 + threadIdx.x;
    if (i < N) {
        int s = 0;
#pragma unroll 8
        for (int p = 0; p < PCH; ++p) s += partial[(size_t)p * N + i];
        deg[i] = s;
    }
}

// exclusive prefix along p over dst-partial; also emits degi, ns, nd
__global__ __launch_bounds__(256) void colprefix_norm_k(u16* __restrict__ partial,
                                                        const int* __restrict__ dego,
                                                        int* __restrict__ degi,
                                                        float* __restrict__ ns,
                                                        float* __restrict__ nd, int N) {
    int i = blockIdx.x * 256 + threadIdx.x;
    if (i < N) {
        int run = 0;
        for (int p = 0; p < PCH; ++p) {
            size_t q = (size_t)p * N + i;
            int v = partial[q];
            partial[q] = (u16)run;
            run += v;
        }
        degi[i] = run;
        int a = dego[i];
        ns[i] = (a > 0) ? rsqrtf((float)a) : 0.0f;
        nd[i] = (run > 0) ? rsqrtf((float)run) : 0.0f;
    }
}

// ---------------- scan for CSR offsets ----------------

__global__ __launch_bounds__(256) void scan1(const int* __restrict__ d, int* __restrict__ off,
                                             int* __restrict__ bsum, int N) {
    __shared__ int s[256];
    int t = threadIdx.x, i = blockIdx.x * 256 + t;
    int v = (i < N) ? d[i] : 0;
    s[t] = v;
    __syncthreads();
    for (int dd = 1; dd < 256; dd <<= 1) {
        int x = (t >= dd) ? s[t - dd] : 0;
        __syncthreads();
        s[t] += x;
        __syncthreads();
    }
    if (i < N) off[i] = s[t] - v;
    if (t == 255) bsum[blockIdx.x] = s[255];
}

__global__ __launch_bounds__(512) void scan2(int* __restrict__ bsum, int nb) {
    __shared__ int s[512];
    int t = threadIdx.x;
    int v = (t < nb) ? bsum[t] : 0;
    s[t] = v;
    __syncthreads();
    for (int dd = 1; dd < 512; dd <<= 1) {
        int x = (t >= dd) ? s[t - dd] : 0;
        __syncthreads();
        s[t] += x;
        __syncthreads();
    }
    if (t < nb) bsum[t] = s[t] - v;
}

__global__ __launch_bounds__(256) void scan3(int* __restrict__ off, const int* __restrict__ bsum,
                                             int N) {
    int i = blockIdx.x * 256 + threadIdx.x;
    if (i < N) off[i] += bsum[blockIdx.x];
}

// ---------------- single-pass CSR scatter (streaming; ranks precomputed) ----------------

__global__ __launch_bounds__(256) void scatter_pass(const int* __restrict__ src,
                                                    const int* __restrict__ dst,
                                                    const int* __restrict__ off,
                                                    const u16* __restrict__ pprefix,
                                                    const u16* __restrict__ rank16,
                                                    u32* __restrict__ epack,
                                                    int N, int E, int chunk) {
    int e = blockIdx.x * 256 + threadIdx.x;
    if (e < E) {
        int d = dst[e];
        int p = e / chunk;
        int pos = off[d] + (int)pprefix[(size_t)p * N + d] + (int)rank16[e];
        epack[pos] = (u32)src[e];
    }
}

// ---------------- fused weight packing to MFMA fragment order ----------------
// B[(ks*NT + nt)*64 + l][j] = (f16) W[ks*32 + (l>>4)*8 + j][nt*16 + (l&15)]

__device__ inline void pack_one(const float* __restrict__ W, half8* __restrict__ out,
                                int tid, int NT, int Ncols) {
    int l  = tid & 63;
    int q  = tid >> 6;
    int nt = q % NT;
    int ks = q / NT;
    int col = nt * 16 + (l & 15);
    int kb  = ks * 32 + ((l >> 4) * 8);
    half8 h;
#pragma unroll
    for (int j = 0; j < 8; ++j) h[j] = (_Float16)W[(kb + j) * Ncols + col];
    out[tid] = h;
}

__global__ __launch_bounds__(256) void wpack_all(const float* __restrict__ W0,
                                                 const float* __restrict__ W1,
                                                 const float* __restrict__ W2,
                                                 half8* __restrict__ B0,
                                                 half8* __restrict__ B1,
                                                 half8* __restrict__ B2) {
    int tid = blockIdx.x * 256 + threadIdx.x;
    if (tid < 4096)      pack_one(W0, B0, tid, 8, 128);
    else if (tid < 6144) pack_one(W1, B1, tid - 4096, 8, 128);
    else if (tid < 6400) pack_one(W2, B2, tid - 6144, 1, 16);
}

// ---------------- mega-block MLP: ALL weights staged in LDS ----------------
// 768 threads = 12 waves; 192 rows/block. LDS: B0 64K | B1 32K | B2 4K | 12x4K H = 148 KB.
// Feat loads issued before the stage copy so HBM latency hides under it.
// Barriers: one __syncthreads after stage; H buffers wave-private.

__global__ __launch_bounds__(768, 3) void mlp_mega(
    const float* __restrict__ feat,
    const float4* __restrict__ Bpack,  // B0|B1|B2 contiguous, 6400 float4
    const float* __restrict__ b0, const float* __restrict__ b1, const float* __restrict__ b2,
    const float* __restrict__ ns,
    float* __restrict__ h0out, _Float16* __restrict__ g0out, int N)
{
    extern __shared__ char lds[];
    const half8* LB0 = (const half8*)lds;              // 4096 frags
    const half8* LB1 = (const half8*)(lds + 65536);    // 2048 frags
    const half8* LB2 = (const half8*)(lds + 98304);    // 256 frags

    const int t  = threadIdx.x;
    const int l  = t & 63;
    const int w  = t >> 6;           // 0..11
    const int cl = l & 15;
    const int qk = l >> 4;
    char* swp = lds + 102400 + w * 4096;  // wave-private H buffer

    const int rowg = blockIdx.x * 192 + w * 16 + cl;
    const int rowc = (rowg < N) ? rowg : (N - 1);

    // issue all 16 feat loads first (independent; land during stage copy)
    const float* ap = feat + (size_t)rowc * F_IN + qk * 8;
    float4 f[16];
#pragma unroll
    for (int ks = 0; ks < 8; ++ks) {
        f[2 * ks]     = *reinterpret_cast<const float4*>(ap + ks * 32);
        f[2 * ks + 1] = *reinterpret_cast<const float4*>(ap + ks * 32 + 4);
    }

    // cooperative stage of all weight fragments (100 KB)
    {
        float4* ldst = (float4*)lds;
        for (int i = t; i < 6400; i += 768) ldst[i] = Bpack[i];
    }
    __syncthreads();

    // convert feat -> f16 A fragments
    half8 a0[8];
#pragma unroll
    for (int ks = 0; ks < 8; ++ks) {
        half8 h;
        h[0] = (_Float16)f[2 * ks].x; h[1] = (_Float16)f[2 * ks].y;
        h[2] = (_Float16)f[2 * ks].z; h[3] = (_Float16)f[2 * ks].w;
        h[4] = (_Float16)f[2 * ks + 1].x; h[5] = (_Float16)f[2 * ks + 1].y;
        h[6] = (_Float16)f[2 * ks + 1].z; h[7] = (_Float16)f[2 * ks + 1].w;
        a0[ks] = h;
    }

    // ---- layer 0 ----
    f32x4 acc0[8];
#pragma unroll
    for (int nt = 0; nt < 8; ++nt) acc0[nt] = (f32x4){0.f, 0.f, 0.f, 0.f};
#pragma unroll
    for (int ks = 0; ks < 8; ++ks)
#pragma unroll
        for (int nt = 0; nt < 8; ++nt)
            acc0[nt] = __builtin_amdgcn_mfma_f32_16x16x32_f16(a0[ks], LB0[(ks * 8 + nt) * 64 + l],
                                                              acc0[nt], 0, 0, 0);
#pragma unroll
    for (int nt = 0; nt < 8; ++nt) {
        float bb = b0[nt * 16 + cl];
#pragma unroll
        for (int r = 0; r < 4; ++r) {
            int orow = qk * 4 + r;
            int byte = orow * 256 + (((nt * 16 + cl) * 2) ^ ((orow & 7) << 4));
            *reinterpret_cast<_Float16*>(swp + byte) = (_Float16)fmaxf(acc0[nt][r] + bb, 0.0f);
        }
    }

    // ---- layer 1 (read all H1 frags to regs, then overwrite with H2) ----
    half8 a1[4];
#pragma unroll
    for (int ks = 0; ks < 4; ++ks) {
        int byte = cl * 256 + (((qk * 8 + ks * 32) * 2) ^ ((cl & 7) << 4));
        a1[ks] = *reinterpret_cast<const half8*>(swp + byte);
    }
    f32x4 acc1[8];
#pragma unroll
    for (int nt = 0; nt < 8; ++nt) acc1[nt] = (f32x4){0.f, 0.f, 0.f, 0.f};
#pragma unroll
    for (int ks = 0; ks < 4; ++ks)
#pragma unroll
        for (int nt = 0; nt < 8; ++nt)
            acc1[nt] = __builtin_amdgcn_mfma_f32_16x16x32_f16(a1[ks], LB1[(ks * 8 + nt) * 64 + l],
                                                              acc1[nt], 0, 0, 0);
#pragma unroll
    for (int nt = 0; nt < 8; ++nt) {
        float bb = b1[nt * 16 + cl];
#pragma unroll
        for (int r = 0; r < 4; ++r) {
            int orow = qk * 4 + r;
            int byte = orow * 256 + (((nt * 16 + cl) * 2) ^ ((orow & 7) << 4));
            *reinterpret_cast<_Float16*>(swp + byte) = (_Float16)fmaxf(acc1[nt][r] + bb, 0.0f);
        }
    }

    // ---- layer 2 ----
    f32x4 acc2 = (f32x4){0.f, 0.f, 0.f, 0.f};
#pragma unroll
    for (int ks = 0; ks < 4; ++ks) {
        int byte = cl * 256 + (((qk * 8 + ks * 32) * 2) ^ ((cl & 7) << 4));
        half8 a2 = *reinterpret_cast<const half8*>(swp + byte);
        acc2 = __builtin_amdgcn_mfma_f32_16x16x32_f16(a2, LB2[ks * 64 + l], acc2, 0, 0, 0);
    }
    float bb2 = b2[cl];
#pragma unroll
    for (int r = 0; r < 4; ++r) {
        int orow = qk * 4 + r;
        int node = blockIdx.x * 192 + w * 16 + orow;
        if (node < N) {
            float hv = acc2[r] + bb2;
            h0out[(size_t)node * C + cl] = hv;
            g0out[(size_t)node * C + cl] = (_Float16)(hv * ns[node]);
        }
    }
}

// ---------------- propagation: gather of pre-scaled f16 g, unroll-8 ----------------

__global__ __launch_bounds__(256) void gatherg(const u32* __restrict__ ep,
                                               const int* __restrict__ off,
                                               const half4* __restrict__ g,
                                               const float4* __restrict__ h0,
                                               const float* __restrict__ ns,
                                               const float* __restrict__ nd,
                                               half4* __restrict__ gnext,
                                               float4* __restrict__ hout,
                                               int N, int E, int last) {
    int gid = blockIdx.x * 256 + threadIdx.x;
    int node = gid >> 2;
    if (node >= N) return;
    int c = gid & 3;
    int o0 = off[node];
    int o1 = (node + 1 < N) ? off[node + 1] : E;
    float k  = 0.9f * nd[node];
    float sc = ns[node];
    float4 hv = h0[gid];
    float4 aA = {0.f, 0.f, 0.f, 0.f};
    float4 aB = {0.f, 0.f, 0.f, 0.f};
    float4 aC = {0.f, 0.f, 0.f, 0.f};
    float4 aD = {0.f, 0.f, 0.f, 0.f};
    int o = o0;
    for (; o + 8 <= o1; o += 8) {
        int s0 = (int)ep[o];     int s1 = (int)ep[o + 1];
        int s2 = (int)ep[o + 2]; int s3 = (int)ep[o + 3];
        int s4 = (int)ep[o + 4]; int s5 = (int)ep[o + 5];
        int s6 = (int)ep[o + 6]; int s7 = (int)ep[o + 7];
        half4 x0 = g[s0 * 4 + c]; half4 x1 = g[s1 * 4 + c];
        half4 x2 = g[s2 * 4 + c]; half4 x3 = g[s3 * 4 + c];
        half4 x4 = g[s4 * 4 + c]; half4 x5 = g[s5 * 4 + c];
        half4 x6 = g[s6 * 4 + c]; half4 x7 = g[s7 * 4 + c];
        aA.x += (float)x0[0]; aA.y += (float)x0[1]; aA.z += (float)x0[2]; aA.w += (float)x0[3];
        aB.x += (float)x1[0]; aB.y += (float)x1[1]; aB.z += (float)x1[2]; aB.w += (float)x1[3];
        aC.x += (float)x2[0]; aC.y += (float)x2[1]; aC.z += (float)x2[2]; aC.w += (float)x2[3];
        aD.x += (float)x3[0]; aD.y += (float)x3[1]; aD.z += (float)x3[2]; aD.w += (float)x3[3];
        aA.x += (float)x4[0]; aA.y += (float)x4[1]; aA.z += (float)x4[2]; aA.w += (float)x4[3];
        aB.x += (float)x5[0]; aB.y += (float)x5[1]; aB.z += (float)x5[2]; aB.w += (float)x5[3];
        aC.x += (float)x6[0]; aC.y += (float)x6[1]; aC.z += (float)x6[2]; aC.w += (float)x6[3];
        aD.x += (float)x7[0]; aD.y += (float)x7[1]; aD.z += (float)x7[2]; aD.w += (float)x7[3];
    }
    for (; o + 2 <= o1; o += 2) {
        int s0 = (int)ep[o];
        int s1 = (int)ep[o + 1];
        half4 x0 = g[s0 * 4 + c];
        half4 x1 = g[s1 * 4 + c];
        aA.x += (float)x0[0]; aA.y += (float)x0[1]; aA.z += (float)x0[2]; aA.w += (float)x0[3];
        aB.x += (float)x1[0]; aB.y += (float)x1[1]; aB.z += (float)x1[2]; aB.w += (float)x1[3];
    }
    if (o < o1) {
        int s0 = (int)ep[o];
        half4 x0 = g[s0 * 4 + c];
        aA.x += (float)x0[0]; aA.y += (float)x0[1]; aA.z += (float)x0[2]; aA.w += (float)x0[3];
    }
    aA.x += aB.x + aC.x + aD.x;
    aA.y += aB.y + aC.y + aD.y;
    aA.z += aB.z + aC.z + aD.z;
    aA.w += aB.w + aC.w + aD.w;
    float4 res;
    res.x = fmaf(k, aA.x, 0.1f * hv.x);
    res.y = fmaf(k, aA.y, 0.1f * hv.y);
    res.z = fmaf(k, aA.z, 0.1f * hv.z);
    res.w = fmaf(k, aA.w, 0.1f * hv.w);
    if (last) {
        hout[gid] = res;
    } else {
        half4 gv;
        gv[0] = (_Float16)(res.x * sc);
        gv[1] = (_Float16)(res.y * sc);
        gv[2] = (_Float16)(res.z * sc);
        gv[3] = (_Float16)(res.w * sc);
        gnext[gid] = gv;
    }
}

// ---------------- launch ----------------

extern "C" void kernel_launch(void* const* d_in, const int* in_sizes, int n_in,
                              void* d_out, int out_size, void* d_ws, size_t ws_size,
                              hipStream_t stream) {
    const float* feat = (const float*)d_in[0];
    const float* W0   = (const float*)d_in[1];
    const float* b0   = (const float*)d_in[2];
    const float* W1   = (const float*)d_in[3];
    const float* b1   = (const float*)d_in[4];
    const float* W2   = (const float*)d_in[5];
    const float* b2   = (const float*)d_in[6];
    const int*   src  = (const int*)d_in[7];
    const int*   dst  = (const int*)d_in[8];

    const int N = in_sizes[0] / F_IN;        // 100000
    const int E = in_sizes[7];               // 1600000
    const int NB = (N + 255) / 256;          // 391
    const int R  = (N + RANGE - 1) / RANGE;  // 7
    const int chunk = (E + PCH - 1) / PCH;   // 12500

    char* base = (char*)d_ws;
    // Region A: partial histogram (u16, 25.6 MB), dead after scatter_pass.
    u16* part = (u16*)base;
    // Region B aliases A: h/g buffers first written AFTER scatter_pass.
    float*    h0 = (float*)base;                                  // 6.4 MB
    _Float16* g0 = (_Float16*)(base + (size_t)N * C * 4);         // 3.2 MB
    _Float16* ga = (_Float16*)(base + (size_t)N * C * 6);         // 3.2 MB
    _Float16* gb = (_Float16*)(base + (size_t)N * C * 8);         // 3.2 MB
    char* ws = base + (size_t)PCH * N * 2;   // = 25.6 MB mark
    int*   dego = (int*)ws;   ws += (size_t)N * 4;
    int*   degi = (int*)ws;   ws += (size_t)N * 4;
    float* ns   = (float*)ws; ws += (size_t)N * 4;
    float* nd   = (float*)ws; ws += (size_t)N * 4;
    int*   off  = (int*)ws;   ws += (size_t)N * 4;
    int*   bsum = (int*)ws;   ws += 512 * 4;
    u16*   rank16 = (u16*)ws; ws += (size_t)E * 2;
    u32*   epack  = (u32*)ws; ws += (size_t)E * 4;
    half8* B0 = (half8*)ws;   ws += 4096 * 16;   // contiguous B0|B1|B2 (staged as one blob)
    half8* B1 = (half8*)ws;   ws += 2048 * 16;
    half8* B2 = (half8*)ws;   ws += 256 * 16;

    // degrees via packed LDS histograms (+rank recording on dst pass)
    hist_k<<<PCH * R, 256, 0, stream>>>(src, part, N, E, R, chunk);
    colsum_k<<<NB, 256, 0, stream>>>(part, dego, N);
    hist_rank_k<<<PCH * R, 256, 0, stream>>>(dst, part, rank16, N, E, R, chunk);
    colprefix_norm_k<<<NB, 256, 0, stream>>>(part, dego, degi, ns, nd, N);

    // CSR offsets + single-pass streaming scatter
    scan1<<<NB, 256, 0, stream>>>(degi, off, bsum, N);
    scan2<<<1, 512, 0, stream>>>(bsum, NB);
    scan3<<<NB, 256, 0, stream>>>(off, bsum, N);
    scatter_pass<<<(E + 255) / 256, 256, 0, stream>>>(src, dst, off, part, rank16, epack, N, E, chunk);

    // MLP (weights packed once, staged to LDS per block)
    wpack_all<<<25, 256, 0, stream>>>(W0, W1, W2, B0, B1, B2);
    mlp_mega<<<(N + 191) / 192, 768, 151552, stream>>>(feat, (const float4*)B0, b0, b1, b2,
                                                       ns, h0, g0, N);

    // propagation
    const _Float16* curg = g0;
    for (int it = 0; it < KITER; ++it) {
        int last = (it == KITER - 1);
        _Float16* nxtg = (it & 1) ? gb : ga;
        gatherg<<<(N * 4 + 255) / 256, 256, 0, stream>>>(epack, off, (const half4*)curg,
                                                         (const float4*)h0, ns, nd,
                                                         (half4*)nxtg, (float4*)d_out, N, E, last);
        curg = nxtg;
    }
}